// Round 6
// baseline (681.279 us; speedup 1.0000x reference)
//
#include <hip/hip_runtime.h>
#include <math.h>

#define NL 8
#define NP 512
#define NC 64
#define NF 128
#define NALL 192
#define NRAY (NL * NP)
#define HID 128

typedef _Float16 half8 __attribute__((ext_vector_type(8)));
typedef float floatx16 __attribute__((ext_vector_type(16)));

#define MFMA(a, b, c) __builtin_amdgcn_mfma_f32_32x32x16_f16((a), (b), (c), 0, 0, 0)

__device__ __forceinline__ float dcoarse_at(int i) {
    float t = (float)i * 0.015625f; // i/64, exact in fp32
    return 1e-3f * (1.0f - t) + 0.5f * t;
}

__device__ __forceinline__ floatx16 fzero16() {
    floatx16 z;
#pragma unroll
    for (int i = 0; i < 16; ++i) z[i] = 0.f;
    return z;
}
__device__ __forceinline__ half8 hzero8() {
    half8 z;
#pragma unroll
    for (int i = 0; i < 8; ++i) z[i] = (_Float16)0.f;
    return z;
}
__device__ __forceinline__ unsigned pack2(_Float16 a, _Float16 b) {
    union { _Float16 h[2]; unsigned u; } P;
    P.h[0] = a; P.h[1] = b;
    return P.u;
}
union H8U { half8 v; unsigned u[4]; };

// Wsp layout (per layer L in {0:w1, 1:w2}, plane p in {hi,lo}):
//   Wsp[(L*2+p)*16384 + f],  f = (((jt*8+ks)*2+lhi)*32 + l31)*8 + i
//   holding split(w[(ks*16+lhi*8+i)*128 + (jt*32+l31)]).
// One A-fragment (jt,ks) = 1 KB contiguous -> fully coalesced wave load.
__global__ void prep_kernel(const float* __restrict__ w1, const float* __restrict__ w2,
                            _Float16* __restrict__ Wsp) {
    int f = blockIdx.x * 256 + threadIdx.x;   // [0, 16384)
    int layer = blockIdx.y;
    const float* w = layer ? w2 : w1;
    int i = f & 7, l31 = (f >> 3) & 31, lhi = (f >> 8) & 1, ks = (f >> 9) & 7, jt = f >> 12;
    int j = jt * 32 + l31;
    int k = ks * 16 + lhi * 8 + i;
    float v = w[k * 128 + j];
    _Float16 hi = (_Float16)v;
    Wsp[(layer * 2 + 0) * 16384 + f] = hi;
    Wsp[(layer * 2 + 1) * 16384 + f] = (_Float16)(v - (float)hi);
}

// Fused 4-layer MLP, split-fp16 MFMA, ZERO LDS / ZERO barriers.
// Each wave independently runs 32 points (m = lane&31) through all layers:
// C tile of layer L is relaid into the B operand of layer L+1 entirely in
// registers (32 shfl_xor(·,32) per transition; C col = B col = lane&31).
// A (weights^T hi/lo) streamed coalesced from Wsp; 4 acc chains per wave.
template<int MODE, int FASTW>   // MODE 0: coarse (d computed), 1: fine (d from d_all)
__global__ __launch_bounds__(256, 3) void mlp_kernel(
    const float* __restrict__ pts, const float* __restrict__ lights,
    const float* __restrict__ d_all,
    const float* __restrict__ w0, const float* __restrict__ b0,
    const float* __restrict__ w1, const float* __restrict__ b1,
    const float* __restrict__ w2, const float* __restrict__ b2,
    const float* __restrict__ w3, const float* __restrict__ b3,
    const _Float16* __restrict__ Wsp,
    float* __restrict__ sdf_out)
{
    const int tid = threadIdx.x;
    const int lane = tid & 63;
    const int wv = tid >> 6;
    const int l31 = lane & 31, lhi = lane >> 5;
    const int mglob = blockIdx.x * 128 + wv * 32 + l31;   // this lane's point

    // ---- per-lane coords (both lhi halves compute the same point's coords)
    int ray; float d;
    if (MODE == 0) { ray = mglob >> 6; d = dcoarse_at(mglob & 63); }
    else           { ray = (int)((unsigned)mglob / 192u); d = d_all[mglob]; }
    int l = ray >> 9, p = ray & (NP - 1);
    float px = pts[p * 3 + 0], py = pts[p * 3 + 1], pz = pts[p * 3 + 2];
    float dx = lights[l * 3 + 0] - px, dy = lights[l * 3 + 1] - py, dz = lights[l * 3 + 2] - pz;
    float n = sqrtf(dx * dx + dy * dy + dz * dz);
    dx /= n; dy /= n; dz /= n;
    float xc[3] = { px + d * dx, py + d * dy, pz + d * dz };

    floatx16 acc[4];
    half8 bh[8], bl[8];

    // C -> next-layer B operand, in registers. For B[ks=2jt+a], halves i<4 come
    // from src lane lhi=0, i>=4 from src lane lhi=1, both from reg-group
    // g = 2a + lhi_dst of C tile jt (j = jt*32 + 8g + 4*lhi_src + q, q=i&3).
    auto make_B = [&](const float* __restrict__ bias) {
#pragma unroll
        for (int jt = 0; jt < 4; ++jt) {
            unsigned ghx[4][2], glx[4][2];
#pragma unroll
            for (int g = 0; g < 4; ++g) {
                const float4 b4 = *(const float4*)&bias[jt * 32 + 8 * g + 4 * lhi];
                float v0 = fmaxf(acc[jt][g * 4 + 0] + b4.x, 0.f);
                float v1 = fmaxf(acc[jt][g * 4 + 1] + b4.y, 0.f);
                float v2 = fmaxf(acc[jt][g * 4 + 2] + b4.z, 0.f);
                float v3 = fmaxf(acc[jt][g * 4 + 3] + b4.w, 0.f);
                _Float16 h0 = (_Float16)v0, h1 = (_Float16)v1;
                _Float16 h2 = (_Float16)v2, h3 = (_Float16)v3;
                ghx[g][0] = pack2(h0, h1);
                ghx[g][1] = pack2(h2, h3);
                glx[g][0] = pack2((_Float16)(v0 - (float)h0), (_Float16)(v1 - (float)h1));
                glx[g][1] = pack2((_Float16)(v2 - (float)h2), (_Float16)(v3 - (float)h3));
            }
#pragma unroll
            for (int a = 0; a < 2; ++a) {
                int gk = 2 * a + lhi;        // group this lane needs
                int gs = 2 * a + (1 - lhi);  // group its partner needs from us
                unsigned oh0 = ghx[gk][0], oh1 = ghx[gk][1];
                unsigned ol0 = glx[gk][0], ol1 = glx[gk][1];
                unsigned rh0 = (unsigned)__shfl_xor((int)ghx[gs][0], 32);
                unsigned rh1 = (unsigned)__shfl_xor((int)ghx[gs][1], 32);
                unsigned rl0 = (unsigned)__shfl_xor((int)glx[gs][0], 32);
                unsigned rl1 = (unsigned)__shfl_xor((int)glx[gs][1], 32);
                H8U BH, BL;
                BH.u[0] = lhi ? rh0 : oh0;  BH.u[1] = lhi ? rh1 : oh1;
                BH.u[2] = lhi ? oh0 : rh0;  BH.u[3] = lhi ? oh1 : rh1;
                BL.u[0] = lhi ? rl0 : ol0;  BL.u[1] = lhi ? rl1 : ol1;
                BL.u[2] = lhi ? ol0 : rl0;  BL.u[3] = lhi ? ol1 : rl1;
                bh[jt * 2 + a] = BH.v;
                bl[jt * 2 + a] = BL.v;
            }
        }
    };

    // ---- Layer 1: 3->128 as one K=16 MFMA step (k>=3 zero-padded)
    {
        half8 a1h[4], a1l[4], bh1 = hzero8(), bl1 = hzero8();
#pragma unroll
        for (int jt = 0; jt < 4; ++jt) { a1h[jt] = hzero8(); a1l[jt] = hzero8(); }
        if (lhi == 0) {
#pragma unroll
            for (int jt = 0; jt < 4; ++jt) {
                int j = jt * 32 + l31;
#pragma unroll
                for (int c = 0; c < 3; ++c) {
                    float v = w0[c * 128 + j];
                    _Float16 hi = (_Float16)v;
                    a1h[jt][c] = hi;
                    a1l[jt][c] = (_Float16)(v - (float)hi);
                }
            }
#pragma unroll
            for (int c = 0; c < 3; ++c) {
                _Float16 hi = (_Float16)xc[c];
                bh1[c] = hi;
                bl1[c] = (_Float16)(xc[c] - (float)hi);
            }
        }
#pragma unroll
        for (int jt = 0; jt < 4; ++jt) acc[jt] = fzero16();
#pragma unroll
        for (int jt = 0; jt < 4; ++jt) acc[jt] = MFMA(a1l[jt], bh1, acc[jt]);
#pragma unroll
        for (int jt = 0; jt < 4; ++jt) acc[jt] = MFMA(a1h[jt], bl1, acc[jt]);
#pragma unroll
        for (int jt = 0; jt < 4; ++jt) acc[jt] = MFMA(a1h[jt], bh1, acc[jt]);
    }
    make_B(b0);   // H1 operand in regs

    // ---- GEMM core: 96 MFMAs streaming A, 4 independent acc chains
    auto gemm = [&](int L, const float* __restrict__ wfull) {
#pragma unroll
        for (int jt = 0; jt < 4; ++jt) acc[jt] = fzero16();
#pragma unroll
        for (int ks = 0; ks < 8; ++ks) {
            half8 ah[4], al[4];
#pragma unroll
            for (int jt = 0; jt < 4; ++jt) {
                if (FASTW) {
                    int off = (((jt * 8 + ks) * 2 + lhi) * 32 + l31) * 8;
                    ah[jt] = *(const half8*)&Wsp[(L * 2 + 0) * 16384 + off];
                    al[jt] = *(const half8*)&Wsp[(L * 2 + 1) * 16384 + off];
                } else {
                    int j = jt * 32 + l31, k0 = ks * 16 + lhi * 8;
#pragma unroll
                    for (int i = 0; i < 8; ++i) {
                        float v = wfull[(k0 + i) * 128 + j];
                        _Float16 hi = (_Float16)v;
                        ah[jt][i] = hi;
                        al[jt][i] = (_Float16)(v - (float)hi);
                    }
                }
            }
#pragma unroll
            for (int jt = 0; jt < 4; ++jt) acc[jt] = MFMA(al[jt], bh[ks], acc[jt]);
#pragma unroll
            for (int jt = 0; jt < 4; ++jt) acc[jt] = MFMA(ah[jt], bl[ks], acc[jt]);
#pragma unroll
            for (int jt = 0; jt < 4; ++jt) acc[jt] = MFMA(ah[jt], bh[ks], acc[jt]);
        }
    };

    // ---- Layer 2 (w1) -> relayout -> Layer 3 (w2)
    gemm(0, w1);
    make_B(b1);
    gemm(1, w2);

    // ---- Layer 4 reduce in regs (same order as previous rounds)
    float pacc = 0.f;
#pragma unroll
    for (int jt = 0; jt < 4; ++jt)
#pragma unroll
        for (int g = 0; g < 4; ++g) {
            int jg = jt * 32 + 8 * g + 4 * lhi;
#pragma unroll
            for (int q = 0; q < 4; ++q) {
                float v = fmaxf(acc[jt][g * 4 + q] + b2[jg + q], 0.f);
                pacc = fmaf(v, w3[jg + q], pacc);
            }
        }
    pacc += __shfl_xor(pacc, 32);
    if (lhi == 0) sdf_out[mglob] = b3[0] + pacc;
}

// One wave per ray, barrier-free: shfl scans for cdf, shfl binary-search for
// sample_pdf (exact searchsorted-count semantics on strictly-increasing cdf),
// then 256-item bitonic sort on 64 lanes x 4 registers (padded with +inf).
__global__ __launch_bounds__(256) void sample_kernel(
    const float* __restrict__ sdf_c, const float* __restrict__ u,
    float* __restrict__ d_all) {
    const int lane = threadIdx.x & 63, wv = threadIdx.x >> 6;
    const int ray = blockIdx.x * 4 + wv;

    // ---- cdf (same math as reference: sigmoid->alpha->T->w->cdf)
    float sv = sdf_c[ray * NC + lane];
    float c = 1.0f / (1.0f + expf(-100.0f * sv));
    float cn = __shfl_down(c, 1);
    bool valid = lane < 63;
    float a = valid ? fmaxf((c - cn) / (c + 1e-10f), 0.f) : 0.f;
    float sh = valid ? (1.f - a + 1e-10f) : 1.f;
    float ps = sh;
#pragma unroll
    for (int off = 1; off < 64; off <<= 1) { float o = __shfl_up(ps, off); if (lane >= off) ps *= o; }
    float T = __shfl_up(ps, 1);
    if (lane == 0) T = 1.f;
    float w = valid ? (a * T + 1e-5f) : 0.f;
    float wsum = w;
#pragma unroll
    for (int off = 1; off < 64; off <<= 1) wsum += __shfl_xor(wsum, off);
    float pdf = w / wsum;
    float cs = pdf;
#pragma unroll
    for (int off = 1; off < 64; off <<= 1) { float o = __shfl_up(cs, off); if (lane >= off) cs += o; }
    float cdfv = __shfl_up(cs, 1);
    if (lane == 0) cdfv = 0.f;    // cdfv = cdf[lane], strictly increasing, cdf[0]=0

    // ---- fine samples: 2 u's per lane -> sort items t=1,2
    float v[4];
    v[0] = dcoarse_at(lane);
    v[3] = __builtin_inff();
#pragma unroll
    for (int t = 0; t < 2; ++t) {
        float uu = u[ray * NF + t * 64 + lane];
        int lo = 0;
#pragma unroll
        for (int b = 32; b >= 1; b >>= 1) {
            float cm = __shfl(cdfv, lo + b);
            if (uu >= cm) lo += b;
        }
        int above = min(lo + 1, NC - 1);
        float cb = __shfl(cdfv, lo), ca = __shfl(cdfv, above);
        float bb = dcoarse_at(lo), ba = dcoarse_at(above);
        float denom = ca - cb;
        if (denom < 1e-5f) denom = 1.f;
        float tt = (uu - cb) / denom;
        v[1 + t] = bb + tt * (ba - bb);
    }

    // ---- bitonic sort, item index i = t*64 + lane
    for (int k = 2; k <= 256; k <<= 1) {
        for (int j = k >> 1; j > 0; j >>= 1) {
            if (j >= 64) {
                int tj = j >> 6;
#pragma unroll
                for (int t = 0; t < 4; ++t) {
                    if ((t & tj) == 0) {
                        int t2 = t ^ tj;
                        bool asc = (((t * 64) & k) == 0);
                        float x = v[t], y = v[t2];
                        bool sw = asc ? (x > y) : (x < y);
                        if (sw) { v[t] = y; v[t2] = x; }
                    }
                }
            } else {
#pragma unroll
                for (int t = 0; t < 4; ++t) {
                    int i = t * 64 + lane;
                    float other = __shfl_xor(v[t], j);
                    bool lower = (lane & j) == 0;
                    bool asc = ((i & k) == 0);
                    v[t] = (lower == asc) ? fminf(v[t], other) : fmaxf(v[t], other);
                }
            }
        }
    }
#pragma unroll
    for (int t = 0; t < 3; ++t) d_all[ray * NALL + t * 64 + lane] = v[t];
}

// One wave per ray: chunked (3/lane) product scan for T, occu sum, out = 1-occu.
__global__ __launch_bounds__(256) void finish_kernel(
    const float* __restrict__ sdf_a, float* __restrict__ out) {
    int lane = threadIdx.x & 63, wv = threadIdx.x >> 6;
    int ray = blockIdx.x * 4 + wv;
    const float* S = sdf_a + (size_t)ray * NALL;
    float c[4];
#pragma unroll
    for (int t = 0; t < 4; ++t) {
        int i = lane * 3 + t;
        c[t] = (i < NALL) ? 1.0f / (1.0f + expf(-100.0f * S[i])) : 0.f;
    }
    float a[3], s[3];
#pragma unroll
    for (int t = 0; t < 3; ++t) {
        int i = lane * 3 + t;
        if (i < NALL - 1) {
            a[t] = fmaxf((c[t] - c[t + 1]) / (c[t] + 1e-10f), 0.f);
            s[t] = 1.f - a[t] + 1e-10f;
        } else { a[t] = 0.f; s[t] = 1.f; }
    }
    float chunk = s[0] * s[1] * s[2];
    float ps = chunk;
#pragma unroll
    for (int off = 1; off < 64; off <<= 1) {
        float o = __shfl_up(ps, off);
        if (lane >= off) ps *= o;
    }
    float T = __shfl_up(ps, 1);
    if (lane == 0) T = 1.f;
    float occ = a[0] * T;
    T *= s[0]; occ = fmaf(a[1], T, occ);
    T *= s[1]; occ = fmaf(a[2], T, occ);
#pragma unroll
    for (int off = 1; off < 64; off <<= 1) occ += __shfl_xor(occ, off);
    if (lane == 0) out[ray] = 1.f - occ;
}

extern "C" void kernel_launch(void* const* d_in, const int* in_sizes, int n_in,
                              void* d_out, int out_size, void* d_ws, size_t ws_size,
                              hipStream_t stream) {
    const float* pts = (const float*)d_in[0];
    const float* lights = (const float*)d_in[1];
    const float* u = (const float*)d_in[2];
    const float* w0 = (const float*)d_in[3];
    const float* b0 = (const float*)d_in[4];
    const float* w1 = (const float*)d_in[5];
    const float* b1 = (const float*)d_in[6];
    const float* w2 = (const float*)d_in[7];
    const float* b2 = (const float*)d_in[8];
    const float* w3 = (const float*)d_in[9];
    const float* b3 = (const float*)d_in[10];
    float* out = (float*)d_out;

    float* ws = (float*)d_ws;
    float* d_all = ws;                          // NRAY*NALL
    float* sdf = ws + (size_t)NRAY * NALL;      // NRAY*NALL (coarse uses first NRAY*NC)

    const size_t base_bytes = (size_t)2 * NRAY * NALL * 4;
    const bool fast = ws_size >= base_bytes + 4 * 16384 * sizeof(_Float16);
    _Float16* Wsp = (_Float16*)((char*)d_ws + base_bytes);

    if (fast) {
        prep_kernel<<<dim3(64, 2), 256, 0, stream>>>(w1, w2, Wsp);
        mlp_kernel<0, 1><<<(NRAY * NC) / 128, 256, 0, stream>>>(
            pts, lights, nullptr, w0, b0, w1, b1, w2, b2, w3, b3, Wsp, sdf);
        sample_kernel<<<NRAY / 4, 256, 0, stream>>>(sdf, u, d_all);
        mlp_kernel<1, 1><<<(NRAY * NALL) / 128, 256, 0, stream>>>(
            pts, lights, d_all, w0, b0, w1, b1, w2, b2, w3, b3, Wsp, sdf);
    } else {
        mlp_kernel<0, 0><<<(NRAY * NC) / 128, 256, 0, stream>>>(
            pts, lights, nullptr, w0, b0, w1, b1, w2, b2, w3, b3, nullptr, sdf);
        sample_kernel<<<NRAY / 4, 256, 0, stream>>>(sdf, u, d_all);
        mlp_kernel<1, 0><<<(NRAY * NALL) / 128, 256, 0, stream>>>(
            pts, lights, d_all, w0, b0, w1, b1, w2, b2, w3, b3, nullptr, sdf);
    }
    finish_kernel<<<NRAY / 4, 256, 0, stream>>>(sdf, out);
}

// Round 7
// 385.476 us; speedup vs baseline: 1.7674x; 1.7674x over previous
//
#include <hip/hip_runtime.h>
#include <math.h>

#define NL 8
#define NP 512
#define NC 64
#define NF 128
#define NALL 192
#define NRAY (NL * NP)
#define HID 128

typedef _Float16 half8 __attribute__((ext_vector_type(8)));
typedef float floatx16 __attribute__((ext_vector_type(16)));

#define MFMA(a, b, c) __builtin_amdgcn_mfma_f32_32x32x16_f16((a), (b), (c), 0, 0, 0)

__device__ __forceinline__ float dcoarse_at(int i) {
    float t = (float)i * 0.015625f; // i/64, exact in fp32
    return 1e-3f * (1.0f - t) + 0.5f * t;
}

__device__ __forceinline__ floatx16 fzero16() {
    floatx16 z;
#pragma unroll
    for (int i = 0; i < 16; ++i) z[i] = 0.f;
    return z;
}
__device__ __forceinline__ half8 hzero8() {
    half8 z;
#pragma unroll
    for (int i = 0; i < 8; ++i) z[i] = (_Float16)0.f;
    return z;
}
__device__ __forceinline__ unsigned pack2(_Float16 a, _Float16 b) {
    union { _Float16 h[2]; unsigned u; } P;
    P.h[0] = a; P.h[1] = b;
    return P.u;
}
union H8U { half8 v; unsigned u[4]; };

// Wsp layout (per layer L in {0:w1, 1:w2}, plane p in {hi,lo}):
//   Wsp[(L*2+p)*16384 + f],  f = (((jt*8+ks)*2+lhi)*32 + l31)*8 + i
//   holding split(w[(ks*16+lhi*8+i)*128 + (jt*32+l31)]).
// One A-fragment (jt,ks) = 1 KB contiguous -> fully coalesced wave load.
__global__ void prep_kernel(const float* __restrict__ w1, const float* __restrict__ w2,
                            _Float16* __restrict__ Wsp) {
    int f = blockIdx.x * 256 + threadIdx.x;   // [0, 16384)
    int layer = blockIdx.y;
    const float* w = layer ? w2 : w1;
    int i = f & 7, l31 = (f >> 3) & 31, lhi = (f >> 8) & 1, ks = (f >> 9) & 7, jt = f >> 12;
    int j = jt * 32 + l31;
    int k = ks * 16 + lhi * 8 + i;
    float v = w[k * 128 + j];
    _Float16 hi = (_Float16)v;
    Wsp[(layer * 2 + 0) * 16384 + f] = hi;
    Wsp[(layer * 2 + 1) * 16384 + f] = (_Float16)(v - (float)hi);
}

// Fused 4-layer MLP, split-fp16 MFMA, ZERO LDS / ZERO barriers.
// Each wave independently runs 32 points (m = lane&31) through all layers:
// C tile of layer L is relaid into the B operand of layer L+1 entirely in
// registers (32 shfl_xor(·,32) per transition; C col = B col = lane&31).
// A (weights^T hi/lo) streamed coalesced from Wsp; 4 acc chains per wave.
// __launch_bounds__(256,2): ~180 live VGPRs needed — (256,3)'s 170-cap spilled
// to scratch (r6: 475MB FETCH / 1.1GB WRITE of spill traffic, 13% MfmaUtil).
template<int MODE, int FASTW>   // MODE 0: coarse (d computed), 1: fine (d from d_all)
__global__ __launch_bounds__(256, 2) void mlp_kernel(
    const float* __restrict__ pts, const float* __restrict__ lights,
    const float* __restrict__ d_all,
    const float* __restrict__ w0, const float* __restrict__ b0,
    const float* __restrict__ w1, const float* __restrict__ b1,
    const float* __restrict__ w2, const float* __restrict__ b2,
    const float* __restrict__ w3, const float* __restrict__ b3,
    const _Float16* __restrict__ Wsp,
    float* __restrict__ sdf_out)
{
    const int tid = threadIdx.x;
    const int lane = tid & 63;
    const int wv = tid >> 6;
    const int l31 = lane & 31, lhi = lane >> 5;
    const int mglob = blockIdx.x * 128 + wv * 32 + l31;   // this lane's point

    // ---- per-lane coords (both lhi halves compute the same point's coords)
    int ray; float d;
    if (MODE == 0) { ray = mglob >> 6; d = dcoarse_at(mglob & 63); }
    else           { ray = (int)((unsigned)mglob / 192u); d = d_all[mglob]; }
    int l = ray >> 9, p = ray & (NP - 1);
    float px = pts[p * 3 + 0], py = pts[p * 3 + 1], pz = pts[p * 3 + 2];
    float dx = lights[l * 3 + 0] - px, dy = lights[l * 3 + 1] - py, dz = lights[l * 3 + 2] - pz;
    float n = sqrtf(dx * dx + dy * dy + dz * dz);
    dx /= n; dy /= n; dz /= n;
    float xc[3] = { px + d * dx, py + d * dy, pz + d * dz };

    floatx16 acc[4];
    half8 bh[8], bl[8];

    // C -> next-layer B operand, in registers. For B[ks=2jt+a], halves i<4 come
    // from src lane lhi=0, i>=4 from src lane lhi=1, both from reg-group
    // g = 2a + lhi_dst of C tile jt (j = jt*32 + 8g + 4*lhi_src + q, q=i&3).
    auto make_B = [&](const float* __restrict__ bias) {
#pragma unroll
        for (int jt = 0; jt < 4; ++jt) {
            unsigned ghx[4][2], glx[4][2];
#pragma unroll
            for (int g = 0; g < 4; ++g) {
                const float4 b4 = *(const float4*)&bias[jt * 32 + 8 * g + 4 * lhi];
                float v0 = fmaxf(acc[jt][g * 4 + 0] + b4.x, 0.f);
                float v1 = fmaxf(acc[jt][g * 4 + 1] + b4.y, 0.f);
                float v2 = fmaxf(acc[jt][g * 4 + 2] + b4.z, 0.f);
                float v3 = fmaxf(acc[jt][g * 4 + 3] + b4.w, 0.f);
                _Float16 h0 = (_Float16)v0, h1 = (_Float16)v1;
                _Float16 h2 = (_Float16)v2, h3 = (_Float16)v3;
                ghx[g][0] = pack2(h0, h1);
                ghx[g][1] = pack2(h2, h3);
                glx[g][0] = pack2((_Float16)(v0 - (float)h0), (_Float16)(v1 - (float)h1));
                glx[g][1] = pack2((_Float16)(v2 - (float)h2), (_Float16)(v3 - (float)h3));
            }
#pragma unroll
            for (int a = 0; a < 2; ++a) {
                int gk = 2 * a + lhi;        // group this lane needs
                int gs = 2 * a + (1 - lhi);  // group its partner needs from us
                unsigned oh0 = ghx[gk][0], oh1 = ghx[gk][1];
                unsigned ol0 = glx[gk][0], ol1 = glx[gk][1];
                unsigned rh0 = (unsigned)__shfl_xor((int)ghx[gs][0], 32);
                unsigned rh1 = (unsigned)__shfl_xor((int)ghx[gs][1], 32);
                unsigned rl0 = (unsigned)__shfl_xor((int)glx[gs][0], 32);
                unsigned rl1 = (unsigned)__shfl_xor((int)glx[gs][1], 32);
                H8U BH, BL;
                BH.u[0] = lhi ? rh0 : oh0;  BH.u[1] = lhi ? rh1 : oh1;
                BH.u[2] = lhi ? oh0 : rh0;  BH.u[3] = lhi ? oh1 : rh1;
                BL.u[0] = lhi ? rl0 : ol0;  BL.u[1] = lhi ? rl1 : ol1;
                BL.u[2] = lhi ? ol0 : rl0;  BL.u[3] = lhi ? ol1 : rl1;
                bh[jt * 2 + a] = BH.v;
                bl[jt * 2 + a] = BL.v;
            }
        }
    };

    // ---- Layer 1: 3->128 as one K=16 MFMA step (k>=3 zero-padded)
    {
        half8 a1h[4], a1l[4], bh1 = hzero8(), bl1 = hzero8();
#pragma unroll
        for (int jt = 0; jt < 4; ++jt) { a1h[jt] = hzero8(); a1l[jt] = hzero8(); }
        if (lhi == 0) {
#pragma unroll
            for (int jt = 0; jt < 4; ++jt) {
                int j = jt * 32 + l31;
#pragma unroll
                for (int c = 0; c < 3; ++c) {
                    float v = w0[c * 128 + j];
                    _Float16 hi = (_Float16)v;
                    a1h[jt][c] = hi;
                    a1l[jt][c] = (_Float16)(v - (float)hi);
                }
            }
#pragma unroll
            for (int c = 0; c < 3; ++c) {
                _Float16 hi = (_Float16)xc[c];
                bh1[c] = hi;
                bl1[c] = (_Float16)(xc[c] - (float)hi);
            }
        }
#pragma unroll
        for (int jt = 0; jt < 4; ++jt) acc[jt] = fzero16();
#pragma unroll
        for (int jt = 0; jt < 4; ++jt) acc[jt] = MFMA(a1l[jt], bh1, acc[jt]);
#pragma unroll
        for (int jt = 0; jt < 4; ++jt) acc[jt] = MFMA(a1h[jt], bl1, acc[jt]);
#pragma unroll
        for (int jt = 0; jt < 4; ++jt) acc[jt] = MFMA(a1h[jt], bh1, acc[jt]);
    }
    make_B(b0);   // H1 operand in regs

    // ---- GEMM core: 96 MFMAs streaming A, 4 independent acc chains
    auto gemm = [&](int L, const float* __restrict__ wfull) {
#pragma unroll
        for (int jt = 0; jt < 4; ++jt) acc[jt] = fzero16();
#pragma unroll
        for (int ks = 0; ks < 8; ++ks) {
            half8 ah[4], al[4];
#pragma unroll
            for (int jt = 0; jt < 4; ++jt) {
                if (FASTW) {
                    int off = (((jt * 8 + ks) * 2 + lhi) * 32 + l31) * 8;
                    ah[jt] = *(const half8*)&Wsp[(L * 2 + 0) * 16384 + off];
                    al[jt] = *(const half8*)&Wsp[(L * 2 + 1) * 16384 + off];
                } else {
                    int j = jt * 32 + l31, k0 = ks * 16 + lhi * 8;
#pragma unroll
                    for (int i = 0; i < 8; ++i) {
                        float v = wfull[(k0 + i) * 128 + j];
                        _Float16 hi = (_Float16)v;
                        ah[jt][i] = hi;
                        al[jt][i] = (_Float16)(v - (float)hi);
                    }
                }
            }
#pragma unroll
            for (int jt = 0; jt < 4; ++jt) acc[jt] = MFMA(al[jt], bh[ks], acc[jt]);
#pragma unroll
            for (int jt = 0; jt < 4; ++jt) acc[jt] = MFMA(ah[jt], bl[ks], acc[jt]);
#pragma unroll
            for (int jt = 0; jt < 4; ++jt) acc[jt] = MFMA(ah[jt], bh[ks], acc[jt]);
        }
    };

    // ---- Layer 2 (w1) -> relayout -> Layer 3 (w2)
    gemm(0, w1);
    make_B(b1);
    gemm(1, w2);

    // ---- Layer 4 reduce in regs (same order as previous rounds)
    float pacc = 0.f;
#pragma unroll
    for (int jt = 0; jt < 4; ++jt)
#pragma unroll
        for (int g = 0; g < 4; ++g) {
            int jg = jt * 32 + 8 * g + 4 * lhi;
#pragma unroll
            for (int q = 0; q < 4; ++q) {
                float v = fmaxf(acc[jt][g * 4 + q] + b2[jg + q], 0.f);
                pacc = fmaf(v, w3[jg + q], pacc);
            }
        }
    pacc += __shfl_xor(pacc, 32);
    if (lhi == 0) sdf_out[mglob] = b3[0] + pacc;
}

// One wave per ray, barrier-free: shfl scans for cdf, shfl binary-search for
// sample_pdf (exact searchsorted-count semantics on strictly-increasing cdf),
// then 256-item bitonic sort on 64 lanes x 4 registers (padded with +inf).
__global__ __launch_bounds__(256) void sample_kernel(
    const float* __restrict__ sdf_c, const float* __restrict__ u,
    float* __restrict__ d_all) {
    const int lane = threadIdx.x & 63, wv = threadIdx.x >> 6;
    const int ray = blockIdx.x * 4 + wv;

    // ---- cdf (same math as reference: sigmoid->alpha->T->w->cdf)
    float sv = sdf_c[ray * NC + lane];
    float c = 1.0f / (1.0f + expf(-100.0f * sv));
    float cn = __shfl_down(c, 1);
    bool valid = lane < 63;
    float a = valid ? fmaxf((c - cn) / (c + 1e-10f), 0.f) : 0.f;
    float sh = valid ? (1.f - a + 1e-10f) : 1.f;
    float ps = sh;
#pragma unroll
    for (int off = 1; off < 64; off <<= 1) { float o = __shfl_up(ps, off); if (lane >= off) ps *= o; }
    float T = __shfl_up(ps, 1);
    if (lane == 0) T = 1.f;
    float w = valid ? (a * T + 1e-5f) : 0.f;
    float wsum = w;
#pragma unroll
    for (int off = 1; off < 64; off <<= 1) wsum += __shfl_xor(wsum, off);
    float pdf = w / wsum;
    float cs = pdf;
#pragma unroll
    for (int off = 1; off < 64; off <<= 1) { float o = __shfl_up(cs, off); if (lane >= off) cs += o; }
    float cdfv = __shfl_up(cs, 1);
    if (lane == 0) cdfv = 0.f;    // cdfv = cdf[lane], strictly increasing, cdf[0]=0

    // ---- fine samples: 2 u's per lane -> sort items t=1,2
    float v[4];
    v[0] = dcoarse_at(lane);
    v[3] = __builtin_inff();
#pragma unroll
    for (int t = 0; t < 2; ++t) {
        float uu = u[ray * NF + t * 64 + lane];
        int lo = 0;
#pragma unroll
        for (int b = 32; b >= 1; b >>= 1) {
            float cm = __shfl(cdfv, lo + b);
            if (uu >= cm) lo += b;
        }
        int above = min(lo + 1, NC - 1);
        float cb = __shfl(cdfv, lo), ca = __shfl(cdfv, above);
        float bb = dcoarse_at(lo), ba = dcoarse_at(above);
        float denom = ca - cb;
        if (denom < 1e-5f) denom = 1.f;
        float tt = (uu - cb) / denom;
        v[1 + t] = bb + tt * (ba - bb);
    }

    // ---- bitonic sort, item index i = t*64 + lane
    for (int k = 2; k <= 256; k <<= 1) {
        for (int j = k >> 1; j > 0; j >>= 1) {
            if (j >= 64) {
                int tj = j >> 6;
#pragma unroll
                for (int t = 0; t < 4; ++t) {
                    if ((t & tj) == 0) {
                        int t2 = t ^ tj;
                        bool asc = (((t * 64) & k) == 0);
                        float x = v[t], y = v[t2];
                        bool sw = asc ? (x > y) : (x < y);
                        if (sw) { v[t] = y; v[t2] = x; }
                    }
                }
            } else {
#pragma unroll
                for (int t = 0; t < 4; ++t) {
                    int i = t * 64 + lane;
                    float other = __shfl_xor(v[t], j);
                    bool lower = (lane & j) == 0;
                    bool asc = ((i & k) == 0);
                    v[t] = (lower == asc) ? fminf(v[t], other) : fmaxf(v[t], other);
                }
            }
        }
    }
#pragma unroll
    for (int t = 0; t < 3; ++t) d_all[ray * NALL + t * 64 + lane] = v[t];
}

// One wave per ray: chunked (3/lane) product scan for T, occu sum, out = 1-occu.
__global__ __launch_bounds__(256) void finish_kernel(
    const float* __restrict__ sdf_a, float* __restrict__ out) {
    int lane = threadIdx.x & 63, wv = threadIdx.x >> 6;
    int ray = blockIdx.x * 4 + wv;
    const float* S = sdf_a + (size_t)ray * NALL;
    float c[4];
#pragma unroll
    for (int t = 0; t < 4; ++t) {
        int i = lane * 3 + t;
        c[t] = (i < NALL) ? 1.0f / (1.0f + expf(-100.0f * S[i])) : 0.f;
    }
    float a[3], s[3];
#pragma unroll
    for (int t = 0; t < 3; ++t) {
        int i = lane * 3 + t;
        if (i < NALL - 1) {
            a[t] = fmaxf((c[t] - c[t + 1]) / (c[t] + 1e-10f), 0.f);
            s[t] = 1.f - a[t] + 1e-10f;
        } else { a[t] = 0.f; s[t] = 1.f; }
    }
    float chunk = s[0] * s[1] * s[2];
    float ps = chunk;
#pragma unroll
    for (int off = 1; off < 64; off <<= 1) {
        float o = __shfl_up(ps, off);
        if (lane >= off) ps *= o;
    }
    float T = __shfl_up(ps, 1);
    if (lane == 0) T = 1.f;
    float occ = a[0] * T;
    T *= s[0]; occ = fmaf(a[1], T, occ);
    T *= s[1]; occ = fmaf(a[2], T, occ);
#pragma unroll
    for (int off = 1; off < 64; off <<= 1) occ += __shfl_xor(occ, off);
    if (lane == 0) out[ray] = 1.f - occ;
}

extern "C" void kernel_launch(void* const* d_in, const int* in_sizes, int n_in,
                              void* d_out, int out_size, void* d_ws, size_t ws_size,
                              hipStream_t stream) {
    const float* pts = (const float*)d_in[0];
    const float* lights = (const float*)d_in[1];
    const float* u = (const float*)d_in[2];
    const float* w0 = (const float*)d_in[3];
    const float* b0 = (const float*)d_in[4];
    const float* w1 = (const float*)d_in[5];
    const float* b1 = (const float*)d_in[6];
    const float* w2 = (const float*)d_in[7];
    const float* b2 = (const float*)d_in[8];
    const float* w3 = (const float*)d_in[9];
    const float* b3 = (const float*)d_in[10];
    float* out = (float*)d_out;

    float* ws = (float*)d_ws;
    float* d_all = ws;                          // NRAY*NALL
    float* sdf = ws + (size_t)NRAY * NALL;      // NRAY*NALL (coarse uses first NRAY*NC)

    const size_t base_bytes = (size_t)2 * NRAY * NALL * 4;
    const bool fast = ws_size >= base_bytes + 4 * 16384 * sizeof(_Float16);
    _Float16* Wsp = (_Float16*)((char*)d_ws + base_bytes);

    if (fast) {
        prep_kernel<<<dim3(64, 2), 256, 0, stream>>>(w1, w2, Wsp);
        mlp_kernel<0, 1><<<(NRAY * NC) / 128, 256, 0, stream>>>(
            pts, lights, nullptr, w0, b0, w1, b1, w2, b2, w3, b3, Wsp, sdf);
        sample_kernel<<<NRAY / 4, 256, 0, stream>>>(sdf, u, d_all);
        mlp_kernel<1, 1><<<(NRAY * NALL) / 128, 256, 0, stream>>>(
            pts, lights, d_all, w0, b0, w1, b1, w2, b2, w3, b3, Wsp, sdf);
    } else {
        mlp_kernel<0, 0><<<(NRAY * NC) / 128, 256, 0, stream>>>(
            pts, lights, nullptr, w0, b0, w1, b1, w2, b2, w3, b3, nullptr, sdf);
        sample_kernel<<<NRAY / 4, 256, 0, stream>>>(sdf, u, d_all);
        mlp_kernel<1, 0><<<(NRAY * NALL) / 128, 256, 0, stream>>>(
            pts, lights, d_all, w0, b0, w1, b1, w2, b2, w3, b3, nullptr, sdf);
    }
    finish_kernel<<<NRAY / 4, 256, 0, stream>>>(sdf, out);
}

// Round 8
// 316.050 us; speedup vs baseline: 2.1556x; 1.2197x over previous
//
#include <hip/hip_runtime.h>
#include <math.h>

#define NL 8
#define NP 512
#define NC 64
#define NF 128
#define NALL 192
#define NRAY (NL * NP)
#define HID 128

typedef _Float16 half8 __attribute__((ext_vector_type(8)));
typedef _Float16 half4v __attribute__((ext_vector_type(4)));
typedef float floatx16 __attribute__((ext_vector_type(16)));

#define MFMA(a, b, c) __builtin_amdgcn_mfma_f32_32x32x16_f16((a), (b), (c), 0, 0, 0)

__device__ __forceinline__ float dcoarse_at(int i) {
    float t = (float)i * 0.015625f; // i/64, exact in fp32
    return 1e-3f * (1.0f - t) + 0.5f * t;
}

__device__ __forceinline__ floatx16 fzero16() {
    floatx16 z;
#pragma unroll
    for (int i = 0; i < 16; ++i) z[i] = 0.f;
    return z;
}
__device__ __forceinline__ half8 hzero8() {
    half8 z;
#pragma unroll
    for (int i = 0; i < 8; ++i) z[i] = (_Float16)0.f;
    return z;
}

// Wsp layout (per layer L in {0:w1, 1:w2}, plane p in {hi,lo}):
//   Wsp[(L*2+p)*16384 + f],  f = (((jt*8+ks)*2+lhi)*32 + l31)*8 + i
//   holding split(w[(ks*16+lhi*8+i)*128 + (jt*32+l31)]).
// One A-fragment (jt,ks) = 1 KB contiguous -> fully coalesced wave load.
__global__ void prep_kernel(const float* __restrict__ w1, const float* __restrict__ w2,
                            _Float16* __restrict__ Wsp) {
    int f = blockIdx.x * 256 + threadIdx.x;   // [0, 16384)
    int layer = blockIdx.y;
    const float* w = layer ? w2 : w1;
    int i = f & 7, l31 = (f >> 3) & 31, lhi = (f >> 8) & 1, ks = (f >> 9) & 7, jt = f >> 12;
    int j = jt * 32 + l31;
    int k = ks * 16 + lhi * 8 + i;
    float v = w[k * 128 + j];
    _Float16 hi = (_Float16)v;
    Wsp[(layer * 2 + 0) * 16384 + f] = hi;
    Wsp[(layer * 2 + 1) * 16384 + f] = (_Float16)(v - (float)hi);
}

// Fused 4-layer MLP over 64 points per block, split-fp16 MFMA.
// Round-4 structure (34 KB LDS, 4 blocks/CU capacity, VGPR ~68) with the
// round-5 16B-chunk XOR swizzle (measured conflict-free): r4's 32B-granule
// swizzle caused 2.5e7 conflict cycles (~21% of block time).
// 4 waves: jh = wv&1 (j-half of 64), mh = wv>>1 (m-tile of 32).
// B (activations) layer-resident in regs; A (weights) streamed coalesced from Wsp.
template<int MODE, int FASTW>   // MODE 0: coarse (d computed), 1: fine (d from d_all)
__global__ __launch_bounds__(256, 3) void mlp_kernel(
    const float* __restrict__ pts, const float* __restrict__ lights,
    const float* __restrict__ d_all,
    const float* __restrict__ w0, const float* __restrict__ b0,
    const float* __restrict__ w1, const float* __restrict__ b1,
    const float* __restrict__ w2, const float* __restrict__ b2,
    const float* __restrict__ w3, const float* __restrict__ b3,
    const _Float16* __restrict__ Wsp,
    float* __restrict__ sdf_out)
{
    __shared__ __align__(16) _Float16 Hhi[64 * 128];
    __shared__ __align__(16) _Float16 Hlo[64 * 128];
    __shared__ _Float16 Xs[6 * 64];   // hi c0,c1,c2 then lo c0,c1,c2
    __shared__ float P2[128];         // [jh][m]

    const int tid = threadIdx.x;
    const int lane = tid & 63;
    const int wv = tid >> 6;
    const int jh = wv & 1, mh = wv >> 1;
    const int l31 = lane & 31, lhi = lane >> 5;
    const int base = blockIdx.x * 64;

    // ---- phase A: per-point coords, split to fp16 hi/lo in LDS
    if (tid < 64) {
        int pt = base + tid;
        int ray; float d;
        if (MODE == 0) { ray = pt >> 6; d = dcoarse_at(pt & 63); }
        else           { ray = (int)((unsigned)pt / 192u); d = d_all[pt]; }
        int l = ray >> 9, p = ray & (NP - 1);
        float px = pts[p * 3 + 0], py = pts[p * 3 + 1], pz = pts[p * 3 + 2];
        float dx = lights[l * 3 + 0] - px, dy = lights[l * 3 + 1] - py, dz = lights[l * 3 + 2] - pz;
        float n = sqrtf(dx * dx + dy * dy + dz * dz);
        dx /= n; dy /= n; dz /= n;
        float xc[3] = { px + d * dx, py + d * dy, pz + d * dz };
#pragma unroll
        for (int c = 0; c < 3; ++c) {
            _Float16 h = (_Float16)xc[c];
            Xs[c * 64 + tid] = h;
            Xs[(3 + c) * 64 + tid] = (_Float16)(xc[c] - (float)h);
        }
    }
    __syncthreads();

    const int m = mh * 32 + l31;   // this lane's point (MFMA C column)
    const int msw = m & 15;

    // 16B-chunk swizzled H address (halves) for element (m, k):
    // chunk = (k>>3) ^ (m&15), offset-in-chunk = k&7  (r5-verified conflict-free)
    auto haddr = [&](int k0) { return m * 128 + ((((k0 >> 3) ^ msw) << 3) | (k0 & 7)); };

    // epilogue helper: bias+relu+split, write C tile (this lane's column m)
    auto store_tile = [&](const floatx16& a, int jt, const float* __restrict__ bias) {
#pragma unroll
        for (int g = 0; g < 4; ++g) {
            int jg = jh * 64 + jt * 32 + 8 * g + 4 * lhi;
            half4v hq, lq;
#pragma unroll
            for (int q = 0; q < 4; ++q) {
                float v = fmaxf(a[g * 4 + q] + bias[jg + q], 0.f);
                _Float16 hi = (_Float16)v;
                hq[q] = hi;
                lq[q] = (_Float16)(v - (float)hi);
            }
            int ad = haddr(jg);
            *(half4v*)&Hhi[ad] = hq;
            *(half4v*)&Hlo[ad] = lq;
        }
    };

    // ---- Layer 1: 3->128 as one K=16 MFMA step (k>=3 zero-padded)
    {
        half8 a1h[2], a1l[2], bh1 = hzero8(), bl1 = hzero8();
#pragma unroll
        for (int jt = 0; jt < 2; ++jt) { a1h[jt] = hzero8(); a1l[jt] = hzero8(); }
        if (lhi == 0) {
#pragma unroll
            for (int jt = 0; jt < 2; ++jt) {
                int j = jh * 64 + jt * 32 + l31;
#pragma unroll
                for (int c = 0; c < 3; ++c) {
                    float v = w0[c * 128 + j];
                    _Float16 hi = (_Float16)v;
                    a1h[jt][c] = hi;
                    a1l[jt][c] = (_Float16)(v - (float)hi);
                }
            }
#pragma unroll
            for (int c = 0; c < 3; ++c) { bh1[c] = Xs[c * 64 + m]; bl1[c] = Xs[(3 + c) * 64 + m]; }
        }
        floatx16 acc0 = fzero16(), acc1 = fzero16();
        acc0 = MFMA(a1l[0], bh1, acc0);
        acc1 = MFMA(a1l[1], bh1, acc1);
        acc0 = MFMA(a1h[0], bl1, acc0);
        acc1 = MFMA(a1h[1], bl1, acc1);
        acc0 = MFMA(a1h[0], bh1, acc0);
        acc1 = MFMA(a1h[1], bh1, acc1);
        store_tile(acc0, 0, b0);
        store_tile(acc1, 1, b0);
    }
    __syncthreads();

    // streamed A-fragment loader (coalesced 1 KB per fragment in FASTW mode)
    auto ldA = [&](int L, int jt, int ks, half8& ah, half8& al) {
        if (FASTW) {
            int off = ((((jh * 2 + jt) * 8 + ks) * 2 + lhi) * 32 + l31) * 8;
            ah = *(const half8*)&Wsp[(L * 2 + 0) * 16384 + off];
            al = *(const half8*)&Wsp[(L * 2 + 1) * 16384 + off];
        } else {
            const float* w = L ? w2 : w1;
            int j = jh * 64 + jt * 32 + l31, k0 = ks * 16 + lhi * 8;
#pragma unroll
            for (int i = 0; i < 8; ++i) {
                float v = w[(k0 + i) * 128 + j];
                _Float16 hi = (_Float16)v;
                ah[i] = hi;
                al[i] = (_Float16)(v - (float)hi);
            }
        }
    };

    half8 bh[8], bl[8];
    floatx16 acc[2];

    // ---- Layer 2: H1 -> H2 (in place, barriered)
#pragma unroll
    for (int ks = 0; ks < 8; ++ks) {
        int ad = haddr(ks * 16 + lhi * 8);
        bh[ks] = *(const half8*)&Hhi[ad];
        bl[ks] = *(const half8*)&Hlo[ad];
    }
    acc[0] = fzero16(); acc[1] = fzero16();
#pragma unroll
    for (int ks = 0; ks < 8; ++ks) {
        half8 ah0, al0, ah1, al1;
        ldA(0, 0, ks, ah0, al0);
        ldA(0, 1, ks, ah1, al1);
        acc[0] = MFMA(al0, bh[ks], acc[0]);
        acc[1] = MFMA(al1, bh[ks], acc[1]);
        acc[0] = MFMA(ah0, bl[ks], acc[0]);
        acc[1] = MFMA(ah1, bl[ks], acc[1]);
        acc[0] = MFMA(ah0, bh[ks], acc[0]);
        acc[1] = MFMA(ah1, bh[ks], acc[1]);
    }
    __syncthreads();   // all waves done reading H1
    store_tile(acc[0], 0, b1);
    store_tile(acc[1], 1, b1);
    __syncthreads();   // H2 visible

    // ---- Layer 3 (+ Layer 4 reduce, no write-back)
#pragma unroll
    for (int ks = 0; ks < 8; ++ks) {
        int ad = haddr(ks * 16 + lhi * 8);
        bh[ks] = *(const half8*)&Hhi[ad];
        bl[ks] = *(const half8*)&Hlo[ad];
    }
    acc[0] = fzero16(); acc[1] = fzero16();
#pragma unroll
    for (int ks = 0; ks < 8; ++ks) {
        half8 ah0, al0, ah1, al1;
        ldA(1, 0, ks, ah0, al0);
        ldA(1, 1, ks, ah1, al1);
        acc[0] = MFMA(al0, bh[ks], acc[0]);
        acc[1] = MFMA(al1, bh[ks], acc[1]);
        acc[0] = MFMA(ah0, bl[ks], acc[0]);
        acc[1] = MFMA(ah1, bl[ks], acc[1]);
        acc[0] = MFMA(ah0, bh[ks], acc[0]);
        acc[1] = MFMA(ah1, bh[ks], acc[1]);
    }
    float p = 0.f;
#pragma unroll
    for (int jt = 0; jt < 2; ++jt)
#pragma unroll
        for (int g = 0; g < 4; ++g) {
            int jg = jh * 64 + jt * 32 + 8 * g + 4 * lhi;
#pragma unroll
            for (int q = 0; q < 4; ++q) {
                float v = fmaxf(acc[jt][g * 4 + q] + b2[jg + q], 0.f);
                p = fmaf(v, w3[jg + q], p);
            }
        }
    p += __shfl_xor(p, 32);
    if (lane < 32) P2[jh * 64 + mh * 32 + l31] = p;
    __syncthreads();
    if (tid < 64) sdf_out[base + tid] = b3[0] + P2[tid] + P2[64 + tid];
}

// One wave per ray, barrier-free: shfl scans for cdf, shfl binary-search for
// sample_pdf (exact searchsorted-count semantics on strictly-increasing cdf),
// then 256-item bitonic sort on 64 lanes x 4 registers (padded with +inf).
__global__ __launch_bounds__(256) void sample_kernel(
    const float* __restrict__ sdf_c, const float* __restrict__ u,
    float* __restrict__ d_all) {
    const int lane = threadIdx.x & 63, wv = threadIdx.x >> 6;
    const int ray = blockIdx.x * 4 + wv;

    // ---- cdf (same math as reference: sigmoid->alpha->T->w->cdf)
    float sv = sdf_c[ray * NC + lane];
    float c = 1.0f / (1.0f + expf(-100.0f * sv));
    float cn = __shfl_down(c, 1);
    bool valid = lane < 63;
    float a = valid ? fmaxf((c - cn) / (c + 1e-10f), 0.f) : 0.f;
    float sh = valid ? (1.f - a + 1e-10f) : 1.f;
    float ps = sh;
#pragma unroll
    for (int off = 1; off < 64; off <<= 1) { float o = __shfl_up(ps, off); if (lane >= off) ps *= o; }
    float T = __shfl_up(ps, 1);
    if (lane == 0) T = 1.f;
    float w = valid ? (a * T + 1e-5f) : 0.f;
    float wsum = w;
#pragma unroll
    for (int off = 1; off < 64; off <<= 1) wsum += __shfl_xor(wsum, off);
    float pdf = w / wsum;
    float cs = pdf;
#pragma unroll
    for (int off = 1; off < 64; off <<= 1) { float o = __shfl_up(cs, off); if (lane >= off) cs += o; }
    float cdfv = __shfl_up(cs, 1);
    if (lane == 0) cdfv = 0.f;    // cdfv = cdf[lane], strictly increasing, cdf[0]=0

    // ---- fine samples: 2 u's per lane -> sort items t=1,2
    float v[4];
    v[0] = dcoarse_at(lane);
    v[3] = __builtin_inff();
#pragma unroll
    for (int t = 0; t < 2; ++t) {
        float uu = u[ray * NF + t * 64 + lane];
        int lo = 0;
#pragma unroll
        for (int b = 32; b >= 1; b >>= 1) {
            float cm = __shfl(cdfv, lo + b);
            if (uu >= cm) lo += b;
        }
        int above = min(lo + 1, NC - 1);
        float cb = __shfl(cdfv, lo), ca = __shfl(cdfv, above);
        float bb = dcoarse_at(lo), ba = dcoarse_at(above);
        float denom = ca - cb;
        if (denom < 1e-5f) denom = 1.f;
        float tt = (uu - cb) / denom;
        v[1 + t] = bb + tt * (ba - bb);
    }

    // ---- bitonic sort, item index i = t*64 + lane
    for (int k = 2; k <= 256; k <<= 1) {
        for (int j = k >> 1; j > 0; j >>= 1) {
            if (j >= 64) {
                int tj = j >> 6;
#pragma unroll
                for (int t = 0; t < 4; ++t) {
                    if ((t & tj) == 0) {
                        int t2 = t ^ tj;
                        bool asc = (((t * 64) & k) == 0);
                        float x = v[t], y = v[t2];
                        bool sw = asc ? (x > y) : (x < y);
                        if (sw) { v[t] = y; v[t2] = x; }
                    }
                }
            } else {
#pragma unroll
                for (int t = 0; t < 4; ++t) {
                    int i = t * 64 + lane;
                    float other = __shfl_xor(v[t], j);
                    bool lower = (lane & j) == 0;
                    bool asc = ((i & k) == 0);
                    v[t] = (lower == asc) ? fminf(v[t], other) : fmaxf(v[t], other);
                }
            }
        }
    }
#pragma unroll
    for (int t = 0; t < 3; ++t) d_all[ray * NALL + t * 64 + lane] = v[t];
}

// One wave per ray: chunked (3/lane) product scan for T, occu sum, out = 1-occu.
__global__ __launch_bounds__(256) void finish_kernel(
    const float* __restrict__ sdf_a, float* __restrict__ out) {
    int lane = threadIdx.x & 63, wv = threadIdx.x >> 6;
    int ray = blockIdx.x * 4 + wv;
    const float* S = sdf_a + (size_t)ray * NALL;
    float c[4];
#pragma unroll
    for (int t = 0; t < 4; ++t) {
        int i = lane * 3 + t;
        c[t] = (i < NALL) ? 1.0f / (1.0f + expf(-100.0f * S[i])) : 0.f;
    }
    float a[3], s[3];
#pragma unroll
    for (int t = 0; t < 3; ++t) {
        int i = lane * 3 + t;
        if (i < NALL - 1) {
            a[t] = fmaxf((c[t] - c[t + 1]) / (c[t] + 1e-10f), 0.f);
            s[t] = 1.f - a[t] + 1e-10f;
        } else { a[t] = 0.f; s[t] = 1.f; }
    }
    float chunk = s[0] * s[1] * s[2];
    float ps = chunk;
#pragma unroll
    for (int off = 1; off < 64; off <<= 1) {
        float o = __shfl_up(ps, off);
        if (lane >= off) ps *= o;
    }
    float T = __shfl_up(ps, 1);
    if (lane == 0) T = 1.f;
    float occ = a[0] * T;
    T *= s[0]; occ = fmaf(a[1], T, occ);
    T *= s[1]; occ = fmaf(a[2], T, occ);
#pragma unroll
    for (int off = 1; off < 64; off <<= 1) occ += __shfl_xor(occ, off);
    if (lane == 0) out[ray] = 1.f - occ;
}

extern "C" void kernel_launch(void* const* d_in, const int* in_sizes, int n_in,
                              void* d_out, int out_size, void* d_ws, size_t ws_size,
                              hipStream_t stream) {
    const float* pts = (const float*)d_in[0];
    const float* lights = (const float*)d_in[1];
    const float* u = (const float*)d_in[2];
    const float* w0 = (const float*)d_in[3];
    const float* b0 = (const float*)d_in[4];
    const float* w1 = (const float*)d_in[5];
    const float* b1 = (const float*)d_in[6];
    const float* w2 = (const float*)d_in[7];
    const float* b2 = (const float*)d_in[8];
    const float* w3 = (const float*)d_in[9];
    const float* b3 = (const float*)d_in[10];
    float* out = (float*)d_out;

    float* ws = (float*)d_ws;
    float* d_all = ws;                          // NRAY*NALL
    float* sdf = ws + (size_t)NRAY * NALL;      // NRAY*NALL (coarse uses first NRAY*NC)

    const size_t base_bytes = (size_t)2 * NRAY * NALL * 4;
    const bool fast = ws_size >= base_bytes + 4 * 16384 * sizeof(_Float16);
    _Float16* Wsp = (_Float16*)((char*)d_ws + base_bytes);

    if (fast) {
        prep_kernel<<<dim3(64, 2), 256, 0, stream>>>(w1, w2, Wsp);
        mlp_kernel<0, 1><<<(NRAY * NC) / 64, 256, 0, stream>>>(
            pts, lights, nullptr, w0, b0, w1, b1, w2, b2, w3, b3, Wsp, sdf);
        sample_kernel<<<NRAY / 4, 256, 0, stream>>>(sdf, u, d_all);
        mlp_kernel<1, 1><<<(NRAY * NALL) / 64, 256, 0, stream>>>(
            pts, lights, d_all, w0, b0, w1, b1, w2, b2, w3, b3, Wsp, sdf);
    } else {
        mlp_kernel<0, 0><<<(NRAY * NC) / 64, 256, 0, stream>>>(
            pts, lights, nullptr, w0, b0, w1, b1, w2, b2, w3, b3, nullptr, sdf);
        sample_kernel<<<NRAY / 4, 256, 0, stream>>>(sdf, u, d_all);
        mlp_kernel<1, 0><<<(NRAY * NALL) / 64, 256, 0, stream>>>(
            pts, lights, d_all, w0, b0, w1, b1, w2, b2, w3, b3, nullptr, sdf);
    }
    finish_kernel<<<NRAY / 4, 256, 0, stream>>>(sdf, out);
}

// Round 9
// 289.281 us; speedup vs baseline: 2.3551x; 1.0925x over previous
//
#include <hip/hip_runtime.h>
#include <math.h>

#define NL 8
#define NP 512
#define NC 64
#define NF 128
#define NALL 192
#define NRAY (NL * NP)
#define HID 128

typedef _Float16 half8 __attribute__((ext_vector_type(8)));
typedef _Float16 half4v __attribute__((ext_vector_type(4)));
typedef float floatx16 __attribute__((ext_vector_type(16)));

#define MFMA(a, b, c) __builtin_amdgcn_mfma_f32_32x32x16_f16((a), (b), (c), 0, 0, 0)

__device__ __forceinline__ float dcoarse_at(int i) {
    float t = (float)i * 0.015625f; // i/64, exact in fp32
    return 1e-3f * (1.0f - t) + 0.5f * t;
}

__device__ __forceinline__ floatx16 fzero16() {
    floatx16 z;
#pragma unroll
    for (int i = 0; i < 16; ++i) z[i] = 0.f;
    return z;
}
__device__ __forceinline__ half8 hzero8() {
    half8 z;
#pragma unroll
    for (int i = 0; i < 8; ++i) z[i] = (_Float16)0.f;
    return z;
}

// Wsp layout (per layer L in {0:w1, 1:w2}, plane p in {hi,lo}):
//   Wsp[(L*2+p)*16384 + f],  f = (((jb*8+ks)*2+lhi)*32 + l31)*8 + i
//   holding split(w[(ks*16+lhi*8+i)*128 + (jb*32+l31)]).
// One A-fragment (jb,ks) = 1 KB contiguous -> fully coalesced wave load.
__global__ void prep_kernel(const float* __restrict__ w1, const float* __restrict__ w2,
                            _Float16* __restrict__ Wsp) {
    int f = blockIdx.x * 256 + threadIdx.x;   // [0, 16384)
    int layer = blockIdx.y;
    const float* w = layer ? w2 : w1;
    int i = f & 7, l31 = (f >> 3) & 31, lhi = (f >> 8) & 1, ks = (f >> 9) & 7, jb = f >> 12;
    int j = jb * 32 + l31;
    int k = ks * 16 + lhi * 8 + i;
    float v = w[k * 128 + j];
    _Float16 hi = (_Float16)v;
    Wsp[(layer * 2 + 0) * 16384 + f] = hi;
    Wsp[(layer * 2 + 1) * 16384 + f] = (_Float16)(v - (float)hi);
}

// Fused 4-layer MLP over 128 points per block, split-fp16 MFMA.
// TRUE QUADRANT waves: wave = (jh = wv&1: j-half 64) x (mh = wv>>1: 64-pt half,
// 2 m-tiles of 32). Per ks, 4 A-fragment loads feed 12 MFMAs in 4 independent
// chains — halves A-stream traffic per point vs r8 (r5 vs r8 showed equal
// A-traffic/pt => equal time; A-stream is the measured limiter, MFMA floor 16us).
// B (activations) layer-resident in regs (128 VGPR); H in LDS w/ 16B-chunk
// XOR swizzle (r5-verified conflict-free).
template<int MODE, int FASTW>   // MODE 0: coarse (d computed), 1: fine (d from d_all)
__global__ __launch_bounds__(256, 2) void mlp_kernel(
    const float* __restrict__ pts, const float* __restrict__ lights,
    const float* __restrict__ d_all,
    const float* __restrict__ w0, const float* __restrict__ b0,
    const float* __restrict__ w1, const float* __restrict__ b1,
    const float* __restrict__ w2, const float* __restrict__ b2,
    const float* __restrict__ w3, const float* __restrict__ b3,
    const _Float16* __restrict__ Wsp,
    float* __restrict__ sdf_out)
{
    __shared__ __align__(16) _Float16 Hhi[128 * 128];
    __shared__ __align__(16) _Float16 Hlo[128 * 128];
    __shared__ _Float16 Xs[6 * 128];   // hi c0,c1,c2 then lo c0,c1,c2
    __shared__ float P2[2 * 128];      // [jh][m]

    const int tid = threadIdx.x;
    const int lane = tid & 63;
    const int wv = tid >> 6;
    const int jh = wv & 1, mh = wv >> 1;
    const int l31 = lane & 31, lhi = lane >> 5;
    const int base = blockIdx.x * 128;

    // ---- phase A: per-point coords, split to fp16 hi/lo in LDS
    if (tid < 128) {
        int pt = base + tid;
        int ray; float d;
        if (MODE == 0) { ray = pt >> 6; d = dcoarse_at(pt & 63); }
        else           { ray = (int)((unsigned)pt / 192u); d = d_all[pt]; }
        int l = ray >> 9, p = ray & (NP - 1);
        float px = pts[p * 3 + 0], py = pts[p * 3 + 1], pz = pts[p * 3 + 2];
        float dx = lights[l * 3 + 0] - px, dy = lights[l * 3 + 1] - py, dz = lights[l * 3 + 2] - pz;
        float n = sqrtf(dx * dx + dy * dy + dz * dz);
        dx /= n; dy /= n; dz /= n;
        float xc[3] = { px + d * dx, py + d * dy, pz + d * dz };
#pragma unroll
        for (int c = 0; c < 3; ++c) {
            _Float16 h = (_Float16)xc[c];
            Xs[c * 128 + tid] = h;
            Xs[(3 + c) * 128 + tid] = (_Float16)(xc[c] - (float)h);
        }
    }
    __syncthreads();

    const int m0 = mh * 64;                 // this wave's 64-pt half
    // lane's point for m-tile mt: m = m0 + mt*32 + l31

    // 16B-chunk swizzled H address (halves) for element (m, k)
    auto haddr = [&](int m, int k0) {
        return m * 128 + ((((k0 >> 3) ^ (m & 15)) << 3) | (k0 & 7));
    };

    // epilogue helper: bias+relu+split, write C tile (column m of tile (jt,mt))
    auto store_tile = [&](const floatx16& a, int jt, int mt, const float* __restrict__ bias) {
        int m = m0 + mt * 32 + l31;
#pragma unroll
        for (int g = 0; g < 4; ++g) {
            int jg = jh * 64 + jt * 32 + 8 * g + 4 * lhi;
            half4v hq, lq;
#pragma unroll
            for (int q = 0; q < 4; ++q) {
                float v = fmaxf(a[g * 4 + q] + bias[jg + q], 0.f);
                _Float16 hi = (_Float16)v;
                hq[q] = hi;
                lq[q] = (_Float16)(v - (float)hi);
            }
            int ad = haddr(m, jg);
            *(half4v*)&Hhi[ad] = hq;
            *(half4v*)&Hlo[ad] = lq;
        }
    };

    floatx16 acc[2][2];   // [jt][mt]

    // ---- Layer 1: 3->128 as one K=16 MFMA step (k>=3 zero-padded)
    {
        half8 a1h[2], a1l[2], bh1[2], bl1[2];
#pragma unroll
        for (int jt = 0; jt < 2; ++jt) { a1h[jt] = hzero8(); a1l[jt] = hzero8(); }
#pragma unroll
        for (int mt = 0; mt < 2; ++mt) { bh1[mt] = hzero8(); bl1[mt] = hzero8(); }
        if (lhi == 0) {
#pragma unroll
            for (int jt = 0; jt < 2; ++jt) {
                int j = jh * 64 + jt * 32 + l31;
#pragma unroll
                for (int c = 0; c < 3; ++c) {
                    float v = w0[c * 128 + j];
                    _Float16 hi = (_Float16)v;
                    a1h[jt][c] = hi;
                    a1l[jt][c] = (_Float16)(v - (float)hi);
                }
            }
#pragma unroll
            for (int mt = 0; mt < 2; ++mt) {
                int m = m0 + mt * 32 + l31;
#pragma unroll
                for (int c = 0; c < 3; ++c) {
                    bh1[mt][c] = Xs[c * 128 + m];
                    bl1[mt][c] = Xs[(3 + c) * 128 + m];
                }
            }
        }
#pragma unroll
        for (int jt = 0; jt < 2; ++jt)
#pragma unroll
            for (int mt = 0; mt < 2; ++mt) acc[jt][mt] = fzero16();
#pragma unroll
        for (int jt = 0; jt < 2; ++jt)
#pragma unroll
            for (int mt = 0; mt < 2; ++mt) acc[jt][mt] = MFMA(a1l[jt], bh1[mt], acc[jt][mt]);
#pragma unroll
        for (int jt = 0; jt < 2; ++jt)
#pragma unroll
            for (int mt = 0; mt < 2; ++mt) acc[jt][mt] = MFMA(a1h[jt], bl1[mt], acc[jt][mt]);
#pragma unroll
        for (int jt = 0; jt < 2; ++jt)
#pragma unroll
            for (int mt = 0; mt < 2; ++mt) acc[jt][mt] = MFMA(a1h[jt], bh1[mt], acc[jt][mt]);
#pragma unroll
        for (int jt = 0; jt < 2; ++jt)
#pragma unroll
            for (int mt = 0; mt < 2; ++mt) store_tile(acc[jt][mt], jt, mt, b0);
    }
    __syncthreads();   // H1 visible

    // streamed A-fragment loader (coalesced 1 KB per fragment in FASTW mode)
    auto ldA = [&](int L, int jt, int ks, half8& ah, half8& al) {
        if (FASTW) {
            int off = ((((jh * 2 + jt) * 8 + ks) * 2 + lhi) * 32 + l31) * 8;
            ah = *(const half8*)&Wsp[(L * 2 + 0) * 16384 + off];
            al = *(const half8*)&Wsp[(L * 2 + 1) * 16384 + off];
        } else {
            const float* w = L ? w2 : w1;
            int j = jh * 64 + jt * 32 + l31, k0 = ks * 16 + lhi * 8;
#pragma unroll
            for (int i = 0; i < 8; ++i) {
                float v = w[(k0 + i) * 128 + j];
                _Float16 hi = (_Float16)v;
                ah[i] = hi;
                al[i] = (_Float16)(v - (float)hi);
            }
        }
    };

    half8 bh[2][8], bl[2][8];   // [mt][ks], 128 VGPR resident

    // GEMM core: read B (both m-tiles), then 8 ks x {4 A loads + 12 MFMA}
    auto gemm = [&](int L) {
#pragma unroll
        for (int mt = 0; mt < 2; ++mt) {
            int m = m0 + mt * 32 + l31;
#pragma unroll
            for (int ks = 0; ks < 8; ++ks) {
                int ad = haddr(m, ks * 16 + lhi * 8);
                bh[mt][ks] = *(const half8*)&Hhi[ad];
                bl[mt][ks] = *(const half8*)&Hlo[ad];
            }
        }
#pragma unroll
        for (int jt = 0; jt < 2; ++jt)
#pragma unroll
            for (int mt = 0; mt < 2; ++mt) acc[jt][mt] = fzero16();
#pragma unroll
        for (int ks = 0; ks < 8; ++ks) {
            half8 ah[2], al[2];
            ldA(L, 0, ks, ah[0], al[0]);
            ldA(L, 1, ks, ah[1], al[1]);
#pragma unroll
            for (int jt = 0; jt < 2; ++jt)
#pragma unroll
                for (int mt = 0; mt < 2; ++mt) acc[jt][mt] = MFMA(al[jt], bh[mt][ks], acc[jt][mt]);
#pragma unroll
            for (int jt = 0; jt < 2; ++jt)
#pragma unroll
                for (int mt = 0; mt < 2; ++mt) acc[jt][mt] = MFMA(ah[jt], bl[mt][ks], acc[jt][mt]);
#pragma unroll
            for (int jt = 0; jt < 2; ++jt)
#pragma unroll
                for (int mt = 0; mt < 2; ++mt) acc[jt][mt] = MFMA(ah[jt], bh[mt][ks], acc[jt][mt]);
        }
    };

    // ---- Layer 2: H1 -> H2 (in place, barriered)
    gemm(0);
    __syncthreads();   // all waves done reading H1 (B2 reads precede gemm)
#pragma unroll
    for (int jt = 0; jt < 2; ++jt)
#pragma unroll
        for (int mt = 0; mt < 2; ++mt) store_tile(acc[jt][mt], jt, mt, b1);
    __syncthreads();   // H2 visible

    // ---- Layer 3 (+ Layer 4 reduce, no write-back)
    gemm(1);
#pragma unroll
    for (int mt = 0; mt < 2; ++mt) {
        float p = 0.f;
#pragma unroll
        for (int jt = 0; jt < 2; ++jt)
#pragma unroll
            for (int g = 0; g < 4; ++g) {
                int jg = jh * 64 + jt * 32 + 8 * g + 4 * lhi;
#pragma unroll
                for (int q = 0; q < 4; ++q) {
                    float v = fmaxf(acc[jt][mt][g * 4 + q] + b2[jg + q], 0.f);
                    p = fmaf(v, w3[jg + q], p);
                }
            }
        p += __shfl_xor(p, 32);
        if (lane < 32) P2[jh * 128 + m0 + mt * 32 + l31] = p;
    }
    __syncthreads();
    if (tid < 128) sdf_out[base + tid] = b3[0] + P2[tid] + P2[128 + tid];
}

// One wave per ray, barrier-free: shfl scans for cdf, shfl binary-search for
// sample_pdf (exact searchsorted-count semantics on strictly-increasing cdf),
// then 256-item bitonic sort on 64 lanes x 4 registers (padded with +inf).
__global__ __launch_bounds__(256) void sample_kernel(
    const float* __restrict__ sdf_c, const float* __restrict__ u,
    float* __restrict__ d_all) {
    const int lane = threadIdx.x & 63, wv = threadIdx.x >> 6;
    const int ray = blockIdx.x * 4 + wv;

    // ---- cdf (same math as reference: sigmoid->alpha->T->w->cdf)
    float sv = sdf_c[ray * NC + lane];
    float c = 1.0f / (1.0f + expf(-100.0f * sv));
    float cn = __shfl_down(c, 1);
    bool valid = lane < 63;
    float a = valid ? fmaxf((c - cn) / (c + 1e-10f), 0.f) : 0.f;
    float sh = valid ? (1.f - a + 1e-10f) : 1.f;
    float ps = sh;
#pragma unroll
    for (int off = 1; off < 64; off <<= 1) { float o = __shfl_up(ps, off); if (lane >= off) ps *= o; }
    float T = __shfl_up(ps, 1);
    if (lane == 0) T = 1.f;
    float w = valid ? (a * T + 1e-5f) : 0.f;
    float wsum = w;
#pragma unroll
    for (int off = 1; off < 64; off <<= 1) wsum += __shfl_xor(wsum, off);
    float pdf = w / wsum;
    float cs = pdf;
#pragma unroll
    for (int off = 1; off < 64; off <<= 1) { float o = __shfl_up(cs, off); if (lane >= off) cs += o; }
    float cdfv = __shfl_up(cs, 1);
    if (lane == 0) cdfv = 0.f;    // cdfv = cdf[lane], strictly increasing, cdf[0]=0

    // ---- fine samples: 2 u's per lane -> sort items t=1,2
    float v[4];
    v[0] = dcoarse_at(lane);
    v[3] = __builtin_inff();
#pragma unroll
    for (int t = 0; t < 2; ++t) {
        float uu = u[ray * NF + t * 64 + lane];
        int lo = 0;
#pragma unroll
        for (int b = 32; b >= 1; b >>= 1) {
            float cm = __shfl(cdfv, lo + b);
            if (uu >= cm) lo += b;
        }
        int above = min(lo + 1, NC - 1);
        float cb = __shfl(cdfv, lo), ca = __shfl(cdfv, above);
        float bb = dcoarse_at(lo), ba = dcoarse_at(above);
        float denom = ca - cb;
        if (denom < 1e-5f) denom = 1.f;
        float tt = (uu - cb) / denom;
        v[1 + t] = bb + tt * (ba - bb);
    }

    // ---- bitonic sort, item index i = t*64 + lane
    for (int k = 2; k <= 256; k <<= 1) {
        for (int j = k >> 1; j > 0; j >>= 1) {
            if (j >= 64) {
                int tj = j >> 6;
#pragma unroll
                for (int t = 0; t < 4; ++t) {
                    if ((t & tj) == 0) {
                        int t2 = t ^ tj;
                        bool asc = (((t * 64) & k) == 0);
                        float x = v[t], y = v[t2];
                        bool sw = asc ? (x > y) : (x < y);
                        if (sw) { v[t] = y; v[t2] = x; }
                    }
                }
            } else {
#pragma unroll
                for (int t = 0; t < 4; ++t) {
                    int i = t * 64 + lane;
                    float other = __shfl_xor(v[t], j);
                    bool lower = (lane & j) == 0;
                    bool asc = ((i & k) == 0);
                    v[t] = (lower == asc) ? fminf(v[t], other) : fmaxf(v[t], other);
                }
            }
        }
    }
#pragma unroll
    for (int t = 0; t < 3; ++t) d_all[ray * NALL + t * 64 + lane] = v[t];
}

// One wave per ray: chunked (3/lane) product scan for T, occu sum, out = 1-occu.
__global__ __launch_bounds__(256) void finish_kernel(
    const float* __restrict__ sdf_a, float* __restrict__ out) {
    int lane = threadIdx.x & 63, wv = threadIdx.x >> 6;
    int ray = blockIdx.x * 4 + wv;
    const float* S = sdf_a + (size_t)ray * NALL;
    float c[4];
#pragma unroll
    for (int t = 0; t < 4; ++t) {
        int i = lane * 3 + t;
        c[t] = (i < NALL) ? 1.0f / (1.0f + expf(-100.0f * S[i])) : 0.f;
    }
    float a[3], s[3];
#pragma unroll
    for (int t = 0; t < 3; ++t) {
        int i = lane * 3 + t;
        if (i < NALL - 1) {
            a[t] = fmaxf((c[t] - c[t + 1]) / (c[t] + 1e-10f), 0.f);
            s[t] = 1.f - a[t] + 1e-10f;
        } else { a[t] = 0.f; s[t] = 1.f; }
    }
    float chunk = s[0] * s[1] * s[2];
    float ps = chunk;
#pragma unroll
    for (int off = 1; off < 64; off <<= 1) {
        float o = __shfl_up(ps, off);
        if (lane >= off) ps *= o;
    }
    float T = __shfl_up(ps, 1);
    if (lane == 0) T = 1.f;
    float occ = a[0] * T;
    T *= s[0]; occ = fmaf(a[1], T, occ);
    T *= s[1]; occ = fmaf(a[2], T, occ);
#pragma unroll
    for (int off = 1; off < 64; off <<= 1) occ += __shfl_xor(occ, off);
    if (lane == 0) out[ray] = 1.f - occ;
}

extern "C" void kernel_launch(void* const* d_in, const int* in_sizes, int n_in,
                              void* d_out, int out_size, void* d_ws, size_t ws_size,
                              hipStream_t stream) {
    const float* pts = (const float*)d_in[0];
    const float* lights = (const float*)d_in[1];
    const float* u = (const float*)d_in[2];
    const float* w0 = (const float*)d_in[3];
    const float* b0 = (const float*)d_in[4];
    const float* w1 = (const float*)d_in[5];
    const float* b1 = (const float*)d_in[6];
    const float* w2 = (const float*)d_in[7];
    const float* b2 = (const float*)d_in[8];
    const float* w3 = (const float*)d_in[9];
    const float* b3 = (const float*)d_in[10];
    float* out = (float*)d_out;

    float* ws = (float*)d_ws;
    float* d_all = ws;                          // NRAY*NALL
    float* sdf = ws + (size_t)NRAY * NALL;      // NRAY*NALL (coarse uses first NRAY*NC)

    const size_t base_bytes = (size_t)2 * NRAY * NALL * 4;
    const bool fast = ws_size >= base_bytes + 4 * 16384 * sizeof(_Float16);
    _Float16* Wsp = (_Float16*)((char*)d_ws + base_bytes);

    if (fast) {
        prep_kernel<<<dim3(64, 2), 256, 0, stream>>>(w1, w2, Wsp);
        mlp_kernel<0, 1><<<(NRAY * NC) / 128, 256, 0, stream>>>(
            pts, lights, nullptr, w0, b0, w1, b1, w2, b2, w3, b3, Wsp, sdf);
        sample_kernel<<<NRAY / 4, 256, 0, stream>>>(sdf, u, d_all);
        mlp_kernel<1, 1><<<(NRAY * NALL) / 128, 256, 0, stream>>>(
            pts, lights, d_all, w0, b0, w1, b1, w2, b2, w3, b3, Wsp, sdf);
    } else {
        mlp_kernel<0, 0><<<(NRAY * NC) / 128, 256, 0, stream>>>(
            pts, lights, nullptr, w0, b0, w1, b1, w2, b2, w3, b3, nullptr, sdf);
        sample_kernel<<<NRAY / 4, 256, 0, stream>>>(sdf, u, d_all);
        mlp_kernel<1, 0><<<(NRAY * NALL) / 128, 256, 0, stream>>>(
            pts, lights, d_all, w0, b0, w1, b1, w2, b2, w3, b3, nullptr, sdf);
    }
    finish_kernel<<<NRAY / 4, 256, 0, stream>>>(sdf, out);
}

// Round 10
// 253.278 us; speedup vs baseline: 2.6898x; 1.1421x over previous
//
#include <hip/hip_runtime.h>
#include <math.h>

#define NL 8
#define NP 512
#define NC 64
#define NF 128
#define NALL 192
#define NRAY (NL * NP)
#define HID 128

typedef _Float16 half8 __attribute__((ext_vector_type(8)));
typedef _Float16 half4v __attribute__((ext_vector_type(4)));
typedef float floatx16 __attribute__((ext_vector_type(16)));
typedef unsigned long long ull;

#define MFMA(a, b, c) __builtin_amdgcn_mfma_f32_32x32x16_f16((a), (b), (c), 0, 0, 0)

__device__ __forceinline__ float dcoarse_at(int i) {
    float t = (float)i * 0.015625f; // i/64, exact in fp32
    return 1e-3f * (1.0f - t) + 0.5f * t;
}

__device__ __forceinline__ floatx16 fzero16() {
    floatx16 z;
#pragma unroll
    for (int i = 0; i < 16; ++i) z[i] = 0.f;
    return z;
}
__device__ __forceinline__ half8 hzero8() {
    half8 z;
#pragma unroll
    for (int i = 0; i < 8; ++i) z[i] = (_Float16)0.f;
    return z;
}

// Wsp layout (per layer L in {0:w1, 1:w2}, plane p in {hi,lo}):
//   Wsp[(L*2+p)*16384 + f],  f = (((jb*8+ks)*2+lhi)*32 + l31)*8 + i
//   holding split(w[(ks*16+lhi*8+i)*128 + (jb*32+l31)]).
__global__ void prep_kernel(const float* __restrict__ w1, const float* __restrict__ w2,
                            _Float16* __restrict__ Wsp) {
    int f = blockIdx.x * 256 + threadIdx.x;   // [0, 16384)
    int layer = blockIdx.y;
    const float* w = layer ? w2 : w1;
    int i = f & 7, l31 = (f >> 3) & 31, lhi = (f >> 8) & 1, ks = (f >> 9) & 7, jb = f >> 12;
    int j = jb * 32 + l31;
    int k = ks * 16 + lhi * 8 + i;
    float v = w[k * 128 + j];
    _Float16 hi = (_Float16)v;
    Wsp[(layer * 2 + 0) * 16384 + f] = hi;
    Wsp[(layer * 2 + 1) * 16384 + f] = (_Float16)(v - (float)hi);
}

// Fused 4-layer MLP over 128 points per block, split-fp16 MFMA (r9 structure:
// true-quadrant waves, 16B-chunk XOR swizzle, B layer-resident, A streamed).
// MODE 0: coarse points (d computed, ray = pt>>6). MODE 1: fine points ONLY
// (d from d_fine, ray = pt>>7) — coarse sdf is NOT recomputed (33% cut); the
// finish kernel gathers via the sort permutation instead.
template<int MODE, int FASTW>
__global__ __launch_bounds__(256, 2) void mlp_kernel(
    const float* __restrict__ pts, const float* __restrict__ lights,
    const float* __restrict__ d_fine,
    const float* __restrict__ w0, const float* __restrict__ b0,
    const float* __restrict__ w1, const float* __restrict__ b1,
    const float* __restrict__ w2, const float* __restrict__ b2,
    const float* __restrict__ w3, const float* __restrict__ b3,
    const _Float16* __restrict__ Wsp,
    float* __restrict__ sdf_out)
{
    __shared__ __align__(16) _Float16 Hhi[128 * 128];
    __shared__ __align__(16) _Float16 Hlo[128 * 128];
    __shared__ _Float16 Xs[6 * 128];   // hi c0,c1,c2 then lo c0,c1,c2
    __shared__ float P2[2 * 128];      // [jh][m]

    const int tid = threadIdx.x;
    const int lane = tid & 63;
    const int wv = tid >> 6;
    const int jh = wv & 1, mh = wv >> 1;
    const int l31 = lane & 31, lhi = lane >> 5;
    const int base = blockIdx.x * 128;

    // ---- phase A: per-point coords, split to fp16 hi/lo in LDS
    if (tid < 128) {
        int pt = base + tid;
        int ray; float d;
        if (MODE == 0) { ray = pt >> 6; d = dcoarse_at(pt & 63); }
        else           { ray = pt >> 7; d = d_fine[pt]; }
        int l = ray >> 9, p = ray & (NP - 1);
        float px = pts[p * 3 + 0], py = pts[p * 3 + 1], pz = pts[p * 3 + 2];
        float dx = lights[l * 3 + 0] - px, dy = lights[l * 3 + 1] - py, dz = lights[l * 3 + 2] - pz;
        float n = sqrtf(dx * dx + dy * dy + dz * dz);
        dx /= n; dy /= n; dz /= n;
        float xc[3] = { px + d * dx, py + d * dy, pz + d * dz };
#pragma unroll
        for (int c = 0; c < 3; ++c) {
            _Float16 h = (_Float16)xc[c];
            Xs[c * 128 + tid] = h;
            Xs[(3 + c) * 128 + tid] = (_Float16)(xc[c] - (float)h);
        }
    }
    __syncthreads();

    const int m0 = mh * 64;                 // this wave's 64-pt half

    auto haddr = [&](int m, int k0) {
        return m * 128 + ((((k0 >> 3) ^ (m & 15)) << 3) | (k0 & 7));
    };

    auto store_tile = [&](const floatx16& a, int jt, int mt, const float* __restrict__ bias) {
        int m = m0 + mt * 32 + l31;
#pragma unroll
        for (int g = 0; g < 4; ++g) {
            int jg = jh * 64 + jt * 32 + 8 * g + 4 * lhi;
            half4v hq, lq;
#pragma unroll
            for (int q = 0; q < 4; ++q) {
                float v = fmaxf(a[g * 4 + q] + bias[jg + q], 0.f);
                _Float16 hi = (_Float16)v;
                hq[q] = hi;
                lq[q] = (_Float16)(v - (float)hi);
            }
            int ad = haddr(m, jg);
            *(half4v*)&Hhi[ad] = hq;
            *(half4v*)&Hlo[ad] = lq;
        }
    };

    floatx16 acc[2][2];   // [jt][mt]

    // ---- Layer 1: 3->128 as one K=16 MFMA step (k>=3 zero-padded)
    {
        half8 a1h[2], a1l[2], bh1[2], bl1[2];
#pragma unroll
        for (int jt = 0; jt < 2; ++jt) { a1h[jt] = hzero8(); a1l[jt] = hzero8(); }
#pragma unroll
        for (int mt = 0; mt < 2; ++mt) { bh1[mt] = hzero8(); bl1[mt] = hzero8(); }
        if (lhi == 0) {
#pragma unroll
            for (int jt = 0; jt < 2; ++jt) {
                int j = jh * 64 + jt * 32 + l31;
#pragma unroll
                for (int c = 0; c < 3; ++c) {
                    float v = w0[c * 128 + j];
                    _Float16 hi = (_Float16)v;
                    a1h[jt][c] = hi;
                    a1l[jt][c] = (_Float16)(v - (float)hi);
                }
            }
#pragma unroll
            for (int mt = 0; mt < 2; ++mt) {
                int m = m0 + mt * 32 + l31;
#pragma unroll
                for (int c = 0; c < 3; ++c) {
                    bh1[mt][c] = Xs[c * 128 + m];
                    bl1[mt][c] = Xs[(3 + c) * 128 + m];
                }
            }
        }
#pragma unroll
        for (int jt = 0; jt < 2; ++jt)
#pragma unroll
            for (int mt = 0; mt < 2; ++mt) acc[jt][mt] = fzero16();
#pragma unroll
        for (int jt = 0; jt < 2; ++jt)
#pragma unroll
            for (int mt = 0; mt < 2; ++mt) acc[jt][mt] = MFMA(a1l[jt], bh1[mt], acc[jt][mt]);
#pragma unroll
        for (int jt = 0; jt < 2; ++jt)
#pragma unroll
            for (int mt = 0; mt < 2; ++mt) acc[jt][mt] = MFMA(a1h[jt], bl1[mt], acc[jt][mt]);
#pragma unroll
        for (int jt = 0; jt < 2; ++jt)
#pragma unroll
            for (int mt = 0; mt < 2; ++mt) acc[jt][mt] = MFMA(a1h[jt], bh1[mt], acc[jt][mt]);
#pragma unroll
        for (int jt = 0; jt < 2; ++jt)
#pragma unroll
            for (int mt = 0; mt < 2; ++mt) store_tile(acc[jt][mt], jt, mt, b0);
    }
    __syncthreads();   // H1 visible

    auto ldA = [&](int L, int jt, int ks, half8& ah, half8& al) {
        if (FASTW) {
            int off = ((((jh * 2 + jt) * 8 + ks) * 2 + lhi) * 32 + l31) * 8;
            ah = *(const half8*)&Wsp[(L * 2 + 0) * 16384 + off];
            al = *(const half8*)&Wsp[(L * 2 + 1) * 16384 + off];
        } else {
            const float* w = L ? w2 : w1;
            int j = jh * 64 + jt * 32 + l31, k0 = ks * 16 + lhi * 8;
#pragma unroll
            for (int i = 0; i < 8; ++i) {
                float v = w[(k0 + i) * 128 + j];
                _Float16 hi = (_Float16)v;
                ah[i] = hi;
                al[i] = (_Float16)(v - (float)hi);
            }
        }
    };

    half8 bh[2][8], bl[2][8];   // [mt][ks], 128 VGPR resident

    auto gemm = [&](int L) {
#pragma unroll
        for (int mt = 0; mt < 2; ++mt) {
            int m = m0 + mt * 32 + l31;
#pragma unroll
            for (int ks = 0; ks < 8; ++ks) {
                int ad = haddr(m, ks * 16 + lhi * 8);
                bh[mt][ks] = *(const half8*)&Hhi[ad];
                bl[mt][ks] = *(const half8*)&Hlo[ad];
            }
        }
#pragma unroll
        for (int jt = 0; jt < 2; ++jt)
#pragma unroll
            for (int mt = 0; mt < 2; ++mt) acc[jt][mt] = fzero16();
#pragma unroll
        for (int ks = 0; ks < 8; ++ks) {
            half8 ah[2], al[2];
            ldA(L, 0, ks, ah[0], al[0]);
            ldA(L, 1, ks, ah[1], al[1]);
#pragma unroll
            for (int jt = 0; jt < 2; ++jt)
#pragma unroll
                for (int mt = 0; mt < 2; ++mt) acc[jt][mt] = MFMA(al[jt], bh[mt][ks], acc[jt][mt]);
#pragma unroll
            for (int jt = 0; jt < 2; ++jt)
#pragma unroll
                for (int mt = 0; mt < 2; ++mt) acc[jt][mt] = MFMA(ah[jt], bl[mt][ks], acc[jt][mt]);
#pragma unroll
            for (int jt = 0; jt < 2; ++jt)
#pragma unroll
                for (int mt = 0; mt < 2; ++mt) acc[jt][mt] = MFMA(ah[jt], bh[mt][ks], acc[jt][mt]);
        }
    };

    // ---- Layer 2: H1 -> H2 (in place, barriered)
    gemm(0);
    __syncthreads();   // all waves done reading H1
#pragma unroll
    for (int jt = 0; jt < 2; ++jt)
#pragma unroll
        for (int mt = 0; mt < 2; ++mt) store_tile(acc[jt][mt], jt, mt, b1);
    __syncthreads();   // H2 visible

    // ---- Layer 3 (+ Layer 4 reduce, no write-back)
    gemm(1);
#pragma unroll
    for (int mt = 0; mt < 2; ++mt) {
        float p = 0.f;
#pragma unroll
        for (int jt = 0; jt < 2; ++jt)
#pragma unroll
            for (int g = 0; g < 4; ++g) {
                int jg = jh * 64 + jt * 32 + 8 * g + 4 * lhi;
#pragma unroll
                for (int q = 0; q < 4; ++q) {
                    float v = fmaxf(acc[jt][mt][g * 4 + q] + b2[jg + q], 0.f);
                    p = fmaf(v, w3[jg + q], p);
                }
            }
        p += __shfl_xor(p, 32);
        if (lane < 32) P2[jh * 128 + m0 + mt * 32 + l31] = p;
    }
    __syncthreads();
    if (tid < 128) sdf_out[base + tid] = b3[0] + P2[tid] + P2[128 + tid];
}

// One wave per ray: shfl scans for cdf, shfl binary-search for sample_pdf
// (exact searchsorted-count semantics on strictly-increasing cdf), then a
// 256-item bitonic KEY-VALUE sort (key = float-bits(d)<<32 | idx; positive
// floats order like uints; +inf pads sort last). Outputs the raw fine d's
// (for the MLP) and the per-ray sorted provenance permutation (for finish).
__global__ __launch_bounds__(256) void sample_kernel(
    const float* __restrict__ sdf_c, const float* __restrict__ u,
    float* __restrict__ d_fine, unsigned char* __restrict__ perm8) {
    const int lane = threadIdx.x & 63, wv = threadIdx.x >> 6;
    const int ray = blockIdx.x * 4 + wv;

    // ---- cdf (same math as reference: sigmoid->alpha->T->w->cdf)
    float sv = sdf_c[ray * NC + lane];
    float c = 1.0f / (1.0f + expf(-100.0f * sv));
    float cn = __shfl_down(c, 1);
    bool valid = lane < 63;
    float a = valid ? fmaxf((c - cn) / (c + 1e-10f), 0.f) : 0.f;
    float sh = valid ? (1.f - a + 1e-10f) : 1.f;
    float ps = sh;
#pragma unroll
    for (int off = 1; off < 64; off <<= 1) { float o = __shfl_up(ps, off); if (lane >= off) ps *= o; }
    float T = __shfl_up(ps, 1);
    if (lane == 0) T = 1.f;
    float w = valid ? (a * T + 1e-5f) : 0.f;
    float wsum = w;
#pragma unroll
    for (int off = 1; off < 64; off <<= 1) wsum += __shfl_xor(wsum, off);
    float pdf = w / wsum;
    float cs = pdf;
#pragma unroll
    for (int off = 1; off < 64; off <<= 1) { float o = __shfl_up(cs, off); if (lane >= off) cs += o; }
    float cdfv = __shfl_up(cs, 1);
    if (lane == 0) cdfv = 0.f;    // cdf[lane], strictly increasing, cdf[0]=0

    // ---- fine samples: 2 u's per lane; write raw values for the MLP
    float df[2];
#pragma unroll
    for (int t = 0; t < 2; ++t) {
        float uu = u[ray * NF + t * 64 + lane];
        int lo = 0;
#pragma unroll
        for (int b = 32; b >= 1; b >>= 1) {
            float cm = __shfl(cdfv, lo + b);
            if (uu >= cm) lo += b;
        }
        int above = min(lo + 1, NC - 1);
        float cb = __shfl(cdfv, lo), ca = __shfl(cdfv, above);
        float bb = dcoarse_at(lo), ba = dcoarse_at(above);
        float denom = ca - cb;
        if (denom < 1e-5f) denom = 1.f;
        float tt = (uu - cb) / denom;
        df[t] = bb + tt * (ba - bb);
        d_fine[ray * 128 + t * 64 + lane] = df[t];
    }

    // ---- key-value bitonic sort, item index i = t*64 + lane
    ull v[4];
    v[0] = ((ull)__float_as_uint(dcoarse_at(lane)) << 32) | (unsigned)lane;
    v[1] = ((ull)__float_as_uint(df[0]) << 32) | (unsigned)(64 + lane);
    v[2] = ((ull)__float_as_uint(df[1]) << 32) | (unsigned)(128 + lane);
    v[3] = ((ull)0x7F800000u << 32) | 255u;   // +inf pad
    for (int k = 2; k <= 256; k <<= 1) {
        for (int j = k >> 1; j > 0; j >>= 1) {
            if (j >= 64) {
                int tj = j >> 6;
#pragma unroll
                for (int t = 0; t < 4; ++t) {
                    if ((t & tj) == 0) {
                        int t2 = t ^ tj;
                        bool asc = (((t * 64) & k) == 0);
                        ull x = v[t], y = v[t2];
                        bool sw = asc ? (x > y) : (x < y);
                        if (sw) { v[t] = y; v[t2] = x; }
                    }
                }
            } else {
#pragma unroll
                for (int t = 0; t < 4; ++t) {
                    int i = t * 64 + lane;
                    ull other = __shfl_xor(v[t], j);
                    bool lower = (lane & j) == 0;
                    bool asc = ((i & k) == 0);
                    bool takeMin = (lower == asc);
                    ull mn = v[t] < other ? v[t] : other;
                    ull mx = v[t] < other ? other : v[t];
                    v[t] = takeMin ? mn : mx;
                }
            }
        }
    }
#pragma unroll
    for (int t = 0; t < 3; ++t)
        perm8[ray * NALL + t * 64 + lane] = (unsigned char)(v[t] & 0xFFu);
}

// One wave per ray: gather sdf via permutation (idx<64 -> coarse, else fine),
// then chunked (3/lane) product scan for T, occu sum, out = 1-occu.
__global__ __launch_bounds__(256) void finish_kernel(
    const float* __restrict__ sdf_c, const float* __restrict__ sdf_f,
    const unsigned char* __restrict__ perm8, float* __restrict__ out) {
    int lane = threadIdx.x & 63, wv = threadIdx.x >> 6;
    int ray = blockIdx.x * 4 + wv;
    const unsigned char* P = perm8 + (size_t)ray * NALL;
    float c[4];
#pragma unroll
    for (int t = 0; t < 4; ++t) {
        int i = lane * 3 + t;
        if (i < NALL) {
            int idx = P[i];
            float s = (idx < 64) ? sdf_c[ray * NC + idx] : sdf_f[ray * 128 + (idx - 64)];
            c[t] = 1.0f / (1.0f + expf(-100.0f * s));
        } else c[t] = 0.f;
    }
    float a[3], s[3];
#pragma unroll
    for (int t = 0; t < 3; ++t) {
        int i = lane * 3 + t;
        if (i < NALL - 1) {
            a[t] = fmaxf((c[t] - c[t + 1]) / (c[t] + 1e-10f), 0.f);
            s[t] = 1.f - a[t] + 1e-10f;
        } else { a[t] = 0.f; s[t] = 1.f; }
    }
    float chunk = s[0] * s[1] * s[2];
    float ps = chunk;
#pragma unroll
    for (int off = 1; off < 64; off <<= 1) {
        float o = __shfl_up(ps, off);
        if (lane >= off) ps *= o;
    }
    float T = __shfl_up(ps, 1);
    if (lane == 0) T = 1.f;
    float occ = a[0] * T;
    T *= s[0]; occ = fmaf(a[1], T, occ);
    T *= s[1]; occ = fmaf(a[2], T, occ);
#pragma unroll
    for (int off = 1; off < 64; off <<= 1) occ += __shfl_xor(occ, off);
    if (lane == 0) out[ray] = 1.f - occ;
}

extern "C" void kernel_launch(void* const* d_in, const int* in_sizes, int n_in,
                              void* d_out, int out_size, void* d_ws, size_t ws_size,
                              hipStream_t stream) {
    const float* pts = (const float*)d_in[0];
    const float* lights = (const float*)d_in[1];
    const float* u = (const float*)d_in[2];
    const float* w0 = (const float*)d_in[3];
    const float* b0 = (const float*)d_in[4];
    const float* w1 = (const float*)d_in[5];
    const float* b1 = (const float*)d_in[6];
    const float* w2 = (const float*)d_in[7];
    const float* b2 = (const float*)d_in[8];
    const float* w3 = (const float*)d_in[9];
    const float* b3 = (const float*)d_in[10];
    float* out = (float*)d_out;

    // ws layout (all 16B-aligned):
    //   sdf_c  : NRAY*64  f32 (1.00 MB)   coarse sdf — persists to finish
    //   sdf_f  : NRAY*128 f32 (2.00 MB)   fine sdf
    //   d_fine : NRAY*128 f32 (2.00 MB)   raw fine sample depths
    //   perm8  : NRAY*192 u8  (0.75 MB)   sorted provenance permutation
    //   Wsp    : 4*16384  f16 (0.125 MB)  split weights
    char* wsb = (char*)d_ws;
    float* sdf_c = (float*)wsb;
    float* sdf_f = (float*)(wsb + (size_t)NRAY * NC * 4);
    float* d_fine = (float*)(wsb + (size_t)NRAY * (NC + 128) * 4);
    unsigned char* perm8 = (unsigned char*)(wsb + (size_t)NRAY * (NC + 256) * 4);
    _Float16* Wsp = (_Float16*)(wsb + (size_t)NRAY * (NC + 256) * 4 + (size_t)NRAY * NALL);
    const size_t need = (size_t)NRAY * (NC + 256) * 4 + (size_t)NRAY * NALL
                      + (size_t)4 * 16384 * sizeof(_Float16);
    const bool fast = ws_size >= need;

    if (fast) {
        prep_kernel<<<dim3(64, 2), 256, 0, stream>>>(w1, w2, Wsp);
        mlp_kernel<0, 1><<<(NRAY * NC) / 128, 256, 0, stream>>>(
            pts, lights, nullptr, w0, b0, w1, b1, w2, b2, w3, b3, Wsp, sdf_c);
        sample_kernel<<<NRAY / 4, 256, 0, stream>>>(sdf_c, u, d_fine, perm8);
        mlp_kernel<1, 1><<<(NRAY * 128) / 128, 256, 0, stream>>>(
            pts, lights, d_fine, w0, b0, w1, b1, w2, b2, w3, b3, Wsp, sdf_f);
    } else {
        mlp_kernel<0, 0><<<(NRAY * NC) / 128, 256, 0, stream>>>(
            pts, lights, nullptr, w0, b0, w1, b1, w2, b2, w3, b3, nullptr, sdf_c);
        sample_kernel<<<NRAY / 4, 256, 0, stream>>>(sdf_c, u, d_fine, perm8);
        mlp_kernel<1, 0><<<(NRAY * 128) / 128, 256, 0, stream>>>(
            pts, lights, d_fine, w0, b0, w1, b1, w2, b2, w3, b3, nullptr, sdf_f);
    }
    finish_kernel<<<NRAY / 4, 256, 0, stream>>>(sdf_c, sdf_f, perm8, out);
}